// Round 20
// baseline (368.733 us; speedup 1.0000x reference)
//
#include <hip/hip_runtime.h>

// ---------- types ----------
typedef __bf16 bf16;
typedef __bf16 bf16x4 __attribute__((ext_vector_type(4)));
typedef __bf16 bf16x8 __attribute__((ext_vector_type(8)));
typedef float  f32x4  __attribute__((ext_vector_type(4)));

__device__ __forceinline__ f32x4 mfma16(bf16x8 a, bf16x8 b, f32x4 c) {
  return __builtin_amdgcn_mfma_f32_16x16x32_bf16(a, b, c, 0, 0, 0);
}
// global -> LDS async copy, 16B per lane. LDS ptr must be wave-uniform base
// (HW adds lane*16); global ptr is per-lane.
__device__ __forceinline__ void load_lds16(const void* g, void* l) {
  __builtin_amdgcn_global_load_lds((__attribute__((address_space(1))) void*)(g),
                                   (__attribute__((address_space(3))) void*)(l),
                                   16, 0, 0);
}

// ---------- elementwise casts ----------
__global__ void cast_bf16(const float* __restrict__ s, bf16* __restrict__ d, int n4) {
  int i = blockIdx.x * blockDim.x + threadIdx.x;
  if (i < n4) {
    float4 v = ((const float4*)s)[i];
    bf16x4 o = { (bf16)v.x, (bf16)v.y, (bf16)v.z, (bf16)v.w };
    *(bf16x4*)(d + (size_t)i * 4) = o;
  }
}

// src[K][N] f32 -> dst[Npad][K] bf16 (rows >= N zeroed)
__global__ void transpose_cast(const float* __restrict__ src, bf16* __restrict__ dst,
                               int K, int N, int Npad) {
  __shared__ float tile[32][33];
  const int n0 = blockIdx.x * 32, k0 = blockIdx.y * 32;
  const int tx = threadIdx.x, ty = threadIdx.y;
#pragma unroll
  for (int i = 0; i < 4; ++i) {
    int k = k0 + ty + i * 8, n = n0 + tx;
    tile[ty + i * 8][tx] = (k < K && n < N) ? src[(size_t)k * N + n] : 0.f;
  }
  __syncthreads();
#pragma unroll
  for (int i = 0; i < 4; ++i) {
    int n = n0 + ty + i * 8, k = k0 + tx;
    if (n < Npad && k < K) dst[(size_t)n * K + k] = (bf16)tile[tx][ty + i * 8];
  }
}

// ---------- GEMM v2 (large-K GEMMs: QKV, KVB): BM=256, BN=128, BK=32 ----------
// 512 threads = 8 waves (4M x 2N), dbuf LDS (48KB -> 3 blocks/CU), stage(t+1)
// issued before compute(t), one barrier per K-step. GROUP_M=8 ordering.
template <typename OutT>
__global__ __launch_bounds__(512) void gemm2_bt(
    const bf16* __restrict__ A, const bf16* __restrict__ Bt, OutT* __restrict__ C,
    int M, int N, int K, int GBM, int GBN) {
  __shared__ alignas(16) bf16 As[2][256 * 32];  // 16KB each
  __shared__ alignas(16) bf16 Bs[2][128 * 32];  //  8KB each
  const int wg = blockIdx.x;
  const int gsz = 8 * GBN;
  const int g = wg / gsz, rem = wg % gsz;
  const int bm = g * 8 + (rem % 8);
  const int bn = rem / 8;

  const int tid = threadIdx.x, wid = tid >> 6, lane = tid & 63;
  const int wr = wid >> 1, wc = wid & 1;  // wave grid 4(M) x 2(N)
  const int lo = lane & 15, hi = lane >> 4;
  const int w64 = wid * 64;

  f32x4 acc[4][4];
#pragma unroll
  for (int m = 0; m < 4; ++m)
#pragma unroll
    for (int n = 0; n < 4; ++n) acc[m][n] = f32x4{0.f, 0.f, 0.f, 0.f};

  const bf16* Abase = A + (size_t)(bm * 256) * K;
  const bf16* Bbase = Bt + (size_t)(bn * 128) * K;

  auto stage = [&](int buf, int kt) {
    int c = w64 + lane;
    load_lds16(Abase + (size_t)(c >> 2) * K + kt + (c & 3) * 8,
               &As[buf][0] + (size_t)w64 * 8);
    int c2 = 512 + w64 + lane;
    load_lds16(Abase + (size_t)(c2 >> 2) * K + kt + (c2 & 3) * 8,
               &As[buf][0] + (size_t)(512 + w64) * 8);
    load_lds16(Bbase + (size_t)(c >> 2) * K + kt + (c & 3) * 8,
               &Bs[buf][0] + (size_t)w64 * 8);
  };

  const int nt = K >> 5;
  stage(0, 0);
  __syncthreads();
  int cur = 0;
  for (int t = 0; t < nt; ++t) {
    if (t + 1 < nt) stage(cur ^ 1, (t + 1) << 5);  // issue prefetch FIRST
    bf16x8 af[4], bfr[4];
#pragma unroll
    for (int m = 0; m < 4; ++m)
      af[m] = *(const bf16x8*)(&As[cur][0] + (size_t)(wr * 64 + m * 16 + lo) * 32 + hi * 8);
#pragma unroll
    for (int n = 0; n < 4; ++n)
      bfr[n] = *(const bf16x8*)(&Bs[cur][0] + (size_t)(wc * 64 + n * 16 + lo) * 32 + hi * 8);
#pragma unroll
    for (int m = 0; m < 4; ++m)
#pragma unroll
      for (int n = 0; n < 4; ++n) acc[m][n] = mfma16(af[m], bfr[n], acc[m][n]);
    __syncthreads();  // drains prefetch DMA; guards buffer reuse
    cur ^= 1;
  }
#pragma unroll
  for (int m = 0; m < 4; ++m)
#pragma unroll
    for (int n = 0; n < 4; ++n)
#pragma unroll
      for (int r = 0; r < 4; ++r) {
        int row = bm * 256 + wr * 64 + m * 16 + hi * 4 + r;
        int col = bn * 128 + wc * 64 + n * 16 + lo;
        C[(size_t)row * N + col] = (OutT)acc[m][n][r];
      }
}

// ---------- GEMM 64x128 (Wo GEMMs): 4 waves (2M x 2N), per-wave 32x64 ------
// r19 analysis: Wo pair at 128^2 is 512 blocks = 2/CU (occupancy-starved,
// ~370 TF). 64x128 tile -> 1024 blocks = 4/CU; A re-read unchanged (16x),
// B re-reads L2-hit (group working set ~2.5MB < 4MB L2 with XCD pinning).
// Same proven 2-barrier m97-family body; only tile/wave mapping changed.
template <typename OutT>
__global__ __launch_bounds__(256) void gemm64_bt(
    const bf16* __restrict__ A, const bf16* __restrict__ Bt, OutT* __restrict__ C,
    int M, int N, int K, int GBN) {
  __shared__ alignas(16) bf16 As[64 * 32];    // 4 KB
  __shared__ alignas(16) bf16 Bs[128 * 32];   // 8 KB
  const int wg = blockIdx.x;
  const int gsz = 8 * GBN;
  const int g = wg / gsz, rem = wg % gsz;
  const int bm = g * 8 + (rem & 7);  // XCD (wg%8) <-> fixed bm within group
  const int bn = rem >> 3;
  const int tid = threadIdx.x, wid = tid >> 6, lane = tid & 63;
  const int wr = wid >> 1, wc = wid & 1;  // wave grid 2(M) x 2(N)
  const int lo = lane & 15, hi = lane >> 4;
  f32x4 acc[2][4];
#pragma unroll
  for (int m = 0; m < 2; ++m)
#pragma unroll
    for (int n = 0; n < 4; ++n) acc[m][n] = f32x4{0.f, 0.f, 0.f, 0.f};

  const bf16* Abase = A + (size_t)(bm * 64) * K;
  const bf16* Bbase = Bt + (size_t)(bn * 128) * K;

  for (int kt = 0; kt < K; kt += 32) {
    __syncthreads();
    {  // A: 256 chunks (1/thread); B: 512 chunks (2/thread)
      int c = tid;
      load_lds16(Abase + (size_t)(c >> 2) * K + kt + (c & 3) * 8, As + (size_t)(c & ~63) * 8);
      load_lds16(Bbase + (size_t)(c >> 2) * K + kt + (c & 3) * 8, Bs + (size_t)(c & ~63) * 8);
      int c2 = 256 + tid;
      load_lds16(Bbase + (size_t)(c2 >> 2) * K + kt + (c2 & 3) * 8,
                 Bs + (size_t)((c2 & ~63)) * 8);
    }
    __syncthreads();
    bf16x8 af[2], bfr[4];
#pragma unroll
    for (int m = 0; m < 2; ++m)
      af[m] = *(const bf16x8*)(As + (size_t)(wr * 32 + m * 16 + lo) * 32 + hi * 8);
#pragma unroll
    for (int n = 0; n < 4; ++n)
      bfr[n] = *(const bf16x8*)(Bs + (size_t)(wc * 64 + n * 16 + lo) * 32 + hi * 8);
#pragma unroll
    for (int m = 0; m < 2; ++m)
#pragma unroll
      for (int n = 0; n < 4; ++n) acc[m][n] = mfma16(af[m], bfr[n], acc[m][n]);
  }
#pragma unroll
  for (int m = 0; m < 2; ++m)
#pragma unroll
    for (int n = 0; n < 4; ++n)
#pragma unroll
      for (int r = 0; r < 4; ++r) {
        int row = bm * 64 + wr * 32 + m * 16 + hi * 4 + r;
        int col = bn * 128 + wc * 64 + n * 16 + lo;
        C[(size_t)row * N + col] = (OutT)acc[m][n][r];
      }
}

// ---------- LayerNorm(512) + RoPE on k_pe (ckv/k_pe read as bf16 from QKVb) ----
__global__ __launch_bounds__(256) void ln_rope(
    const bf16* __restrict__ QKVb, const float* __restrict__ g, const float* __restrict__ bta,
    const int* __restrict__ pos, const float* __restrict__ cosT, const float* __restrict__ sinT,
    bf16* __restrict__ LNout, float* __restrict__ KPE) {
  const int row = blockIdx.x, tid = threadIdx.x;
  const bf16* x = QKVb + (size_t)row * 3712 + 3072;
  float v0 = (float)x[tid], v1 = (float)x[tid + 256];
  float s = v0 + v1, s2 = v0 * v0 + v1 * v1;
#pragma unroll
  for (int off = 1; off < 64; off <<= 1) {
    s += __shfl_xor(s, off, 64);
    s2 += __shfl_xor(s2, off, 64);
  }
  __shared__ float red[8];
  const int wid = tid >> 6;
  if ((tid & 63) == 0) { red[wid] = s; red[4 + wid] = s2; }
  __syncthreads();
  s = red[0] + red[1] + red[2] + red[3];
  s2 = red[4] + red[5] + red[6] + red[7];
  const float mu = s * (1.f / 512.f);
  const float var = s2 * (1.f / 512.f) - mu * mu;
  const float rstd = rsqrtf(var + 1e-6f);
  LNout[(size_t)row * 512 + tid] = (bf16)((v0 - mu) * rstd * g[tid] + bta[tid]);
  LNout[(size_t)row * 512 + tid + 256] = (bf16)((v1 - mu) * rstd * g[tid + 256] + bta[tid + 256]);
  if (tid < 64) {
    float kvp = (float)x[512 + tid];
    float partner = (float)x[512 + (tid ^ 32)];
    float rot = (tid < 32) ? -partner : partner;
    int p = pos[row];
    KPE[(size_t)row * 64 + tid] = kvp * cosT[p * 64 + tid] + rot * sinT[p * 64 + tid];
  }
}

// ---------- pack K: [b][h][s][200] (rows padded 192->200, pad zeroed) ----------
__global__ void pack_k(const bf16* __restrict__ KVb, const float* __restrict__ KPE,
                       bf16* __restrict__ Kh) {
  const int h = blockIdx.x, row = blockIdx.y;
  const int t = threadIdx.x;
  const bf16* kv = KVb + (size_t)row * 4096 + h * 256;
  bf16* o = Kh + ((size_t)((row >> 11) * 16 + h) * 2048 + (row & 2047)) * 200;
  o[t] = kv[t];
  o[t + 64] = kv[t + 64];
  o[128 + t] = (bf16)KPE[(size_t)row * 64 + t];
  if (t < 8) o[192 + t] = (bf16)0.f;
}

// ---------- V transpose: [b][h][kv_tile][128 d][72 kv] (pad zeroed) ----------
__global__ void transpose_v(const bf16* __restrict__ KVb, bf16* __restrict__ Vt) {
  __shared__ bf16 tile[32][33];
  const int bh = blockIdx.x, st = blockIdx.y, dt = blockIdx.z;
  const int b = bh >> 4, h = bh & 15;
  const int tx = threadIdx.x, ty = threadIdx.y;
#pragma unroll
  for (int i = 0; i < 4; ++i) {
    int sIdx = st * 32 + ty + i * 8;
    tile[ty + i * 8][tx] = KVb[(size_t)(b * 2048 + sIdx) * 4096 + h * 256 + 128 + dt * 32 + tx];
  }
  __syncthreads();
  const int kt = st >> 1;
  const int kvl = (st & 1) * 32;
#pragma unroll
  for (int i = 0; i < 4; ++i) {
    int d = dt * 32 + ty + i * 8;
    size_t rowbase = ((size_t)(bh * 32 + kt) * 128 + d) * 72;
    Vt[rowbase + kvl + tx] = tile[tx][ty + i * 8];
    if ((st & 1) && tx < 8) Vt[rowbase + 64 + tx] = (bf16)0.f;
  }
}

// ---------- flash attention (causal) v6 + fused Q-RoPE prologue ----------
// Measured optimum of this structure family (r13/r19: ~107us). 52 KiB LDS ->
// 3 blocks/CU; ones-MFMA rowsum; setprio around MFMA clusters; LPT qt order.
__global__ __launch_bounds__(256, 3) void flash_attn(
    const bf16* __restrict__ QKVb, const int* __restrict__ pos,
    const float* __restrict__ cosT, const float* __restrict__ sinT,
    const bf16* __restrict__ Kh, const bf16* __restrict__ Vt,
    bf16* __restrict__ Ob) {
  __shared__ alignas(16) bf16 Ks[64 * 200];   // 25600 B
  __shared__ alignas(16) bf16 Vs[128 * 72];   // 18432 B
  __shared__ alignas(16) bf16 Ps[4][16 * 72]; //  9216 B
  const int bh = blockIdx.x, qt = 31 - blockIdx.y;  // longest blocks first
  const int b = bh >> 4, h = bh & 15;
  const int tid = threadIdx.x, wid = tid >> 6, lane = tid & 63;
  const int lo = lane & 15, hi = lane >> 4;
  const int q0 = qt * 64 + wid * 16;

  bf16x8 qf[6];
  {
    const int grow_i = b * 2048 + q0 + lo;
    const bf16* qsrc = QKVb + (size_t)grow_i * 3712 + h * 192 + hi * 8;
    bf16x8 raw[6];
#pragma unroll
    for (int kg = 0; kg < 6; ++kg) raw[kg] = *(const bf16x8*)(qsrc + kg * 32);
    const float scale = 0.07216878364870322f;  // 1/sqrt(192)
#pragma unroll
    for (int kg = 0; kg < 4; ++kg)
#pragma unroll
      for (int j = 0; j < 8; ++j) qf[kg][j] = (bf16)((float)raw[kg][j] * scale);
    const int p = pos[grow_i];
    const float* cb = cosT + p * 64 + hi * 8;
    const float* sb = sinT + p * 64 + hi * 8;
#pragma unroll
    for (int j = 0; j < 8; ++j) {
      float q4 = (float)raw[4][j], q5 = (float)raw[5][j];
      qf[4][j] = (bf16)((q4 * cb[j] - q5 * sb[j]) * scale);            // d<32: rot=-partner
      qf[5][j] = (bf16)((q5 * cb[32 + j] + q4 * sb[32 + j]) * scale);  // d>=32: rot=+partner
    }
  }
  float m_r[4] = {-INFINITY, -INFINITY, -INFINITY, -INFINITY};
  f32x4 accl = f32x4{0.f, 0.f, 0.f, 0.f};  // row-sum accumulator (l), D-layout
  f32x4 acc[8];
#pragma unroll
  for (int v = 0; v < 8; ++v) acc[v] = f32x4{0.f, 0.f, 0.f, 0.f};
  const bf16 one_b = (bf16)1.f;
  const bf16x8 ones = {one_b, one_b, one_b, one_b, one_b, one_b, one_b, one_b};

  const bf16* Kbase = Kh + (size_t)bh * 2048 * 200;
  const bf16* Vbase = Vt + (size_t)bh * 32 * (128 * 72);
  bf16* Pw = &Ps[wid][0];

  const int last = qt * 64;
  for (int kv0 = 0; kv0 <= last; kv0 += 64) {
    // stage K(t) + V(t); buffers free per barrier #2 of previous iter
    {
      const bf16* srcK = Kbase + (size_t)kv0 * 200;
      for (int c0 = wid * 64; c0 < 1600; c0 += 256)
        load_lds16(srcK + (size_t)(c0 + lane) * 8, Ks + (size_t)c0 * 8);
      const bf16* srcV = Vbase + (size_t)(kv0 >> 6) * (128 * 72);
      for (int c0 = wid * 64; c0 < 1152; c0 += 256)
        load_lds16(srcV + (size_t)(c0 + lane) * 8, Vs + (size_t)c0 * 8);
    }
    __syncthreads();  // #1: drain DMA (vmcnt0)

    // S = Q K^T  (per wave: 16 q x 64 kv)
    f32x4 sacc[4];
    __builtin_amdgcn_s_setprio(1);
#pragma unroll
    for (int nk = 0; nk < 4; ++nk) {
      sacc[nk] = f32x4{0.f, 0.f, 0.f, 0.f};
#pragma unroll
      for (int kg = 0; kg < 6; ++kg) {
        bf16x8 kf = *(const bf16x8*)(Ks + (size_t)(nk * 16 + lo) * 200 + kg * 32 + hi * 8);
        sacc[nk] = mfma16(qf[kg], kf, sacc[nk]);
      }
    }
    __builtin_amdgcn_s_setprio(0);
    if (kv0 == last) {  // diagonal tile: causal mask
#pragma unroll
      for (int nk = 0; nk < 4; ++nk)
#pragma unroll
        for (int r = 0; r < 4; ++r)
          if (kv0 + nk * 16 + lo > q0 + hi * 4 + r) sacc[nk][r] = -INFINITY;
    }
    // online softmax: max-reduce only (sum via ones-MFMA)
    float sc[4];
#pragma unroll
    for (int r = 0; r < 4; ++r) {
      float mx = fmaxf(fmaxf(sacc[0][r], sacc[1][r]), fmaxf(sacc[2][r], sacc[3][r]));
      mx = fmaxf(mx, __shfl_xor(mx, 1, 64));
      mx = fmaxf(mx, __shfl_xor(mx, 2, 64));
      mx = fmaxf(mx, __shfl_xor(mx, 4, 64));
      mx = fmaxf(mx, __shfl_xor(mx, 8, 64));
      float mnew = fmaxf(m_r[r], mx);
      sc[r] = __expf(m_r[r] - mnew);
      m_r[r] = mnew;
    }
#pragma unroll
    for (int nk = 0; nk < 4; ++nk)
#pragma unroll
      for (int r = 0; r < 4; ++r) {
        float p = __expf(sacc[nk][r] - m_r[r]);
        Pw[(hi * 4 + r) * 72 + nk * 16 + lo] = (bf16)p;
      }
#pragma unroll
    for (int r = 0; r < 4; ++r) {
      accl[r] *= sc[r];
#pragma unroll
      for (int v = 0; v < 8; ++v) acc[v][r] *= sc[r];
    }
    // P fragments (own-wave region; same-wave RAW via lgkmcnt, no barrier)
    bf16x8 pf0 = *(const bf16x8*)(Pw + (size_t)lo * 72 + hi * 8);
    bf16x8 pf1 = *(const bf16x8*)(Pw + (size_t)lo * 72 + 32 + hi * 8);
    __builtin_amdgcn_s_setprio(1);
    accl = mfma16(pf0, ones, accl);
    accl = mfma16(pf1, ones, accl);
    // PV: P (16 x 64) @ V (64 x 128); Vs holds V^T [d][kv]
#pragma unroll
    for (int v = 0; v < 8; ++v) {
      const bf16* vrow = Vs + (size_t)(v * 16 + lo) * 72 + hi * 8;
      bf16x8 vf0 = *(const bf16x8*)(vrow);
      bf16x8 vf1 = *(const bf16x8*)(vrow + 32);
      acc[v] = mfma16(pf0, vf0, acc[v]);
      acc[v] = mfma16(pf1, vf1, acc[v]);
    }
    __builtin_amdgcn_s_setprio(0);
    __syncthreads();  // #2: all K/V/P reads done before next tile's stage
  }
  // epilogue: O /= l, write bf16 to Ob[b][q][h*128+d]
#pragma unroll
  for (int r = 0; r < 4; ++r) {
    float invl = 1.f / accl[r];
    int qrow = q0 + hi * 4 + r;
    bf16* orow = Ob + ((size_t)b * 2048 + qrow) * 2048 + h * 128 + lo;
#pragma unroll
    for (int v = 0; v < 8; ++v) orow[v * 16] = (bf16)(acc[v][r] * invl);
  }
}

// ---------- launcher ----------
extern "C" void kernel_launch(void* const* d_in, const int* in_sizes, int n_in,
                              void* d_out, int out_size, void* d_ws, size_t ws_size,
                              hipStream_t stream) {
  const float* hidden = (const float*)d_in[0];
  const int* pos = (const int*)d_in[1];
  const float* cosT = (const float*)d_in[2];
  const float* sinT = (const float*)d_in[3];
  const float* W_q = (const float*)d_in[4];
  const float* W_kva = (const float*)d_in[5];
  const float* g = (const float*)d_in[6];
  const float* bta = (const float*)d_in[7];
  const float* W_kvb = (const float*)d_in[8];
  const float* W_o = (const float*)d_in[9];
  float* out = (float*)d_out;

  char* w = (char*)d_ws;
  size_t used = 0;
  auto carve = [&](size_t bytes) -> char* {
    char* p = w;
    size_t pad = (bytes + 255) & ~(size_t)255;
    w += pad;
    used += pad;
    return p;
  };
  bf16* Xb = (bf16*)carve(16777216);        // [4096][2048]
  bf16* Wqkva_t = (bf16*)carve(15204352);   // [3712][2048]: Wq rows 0..3071, Wkva rows 3072..3711
  bf16* Wkvb_t = (bf16*)carve(4194304);     // [4096][512]
  bf16* Wo_t = (bf16*)carve(8388608);       // [2048][2048]
  bf16* QKVb = (bf16*)carve(30408704);      // [4096][3712] (read by flash_attn; NOT aliased)
  bf16* Ob = (bf16*)carve(16777216);        // [4096][2048] dedicated
  bf16* LNout = (bf16*)carve(4194304);      // [4096][512]
  float* KPE = (float*)carve(1048576);      // [4096][64] f32
  char* KVT1 = carve(33554432);             // KVb [4096][4096]; reused as T1b [4096][2048]
  bf16* KVb = (bf16*)KVT1;
  bf16* T1b = (bf16*)KVT1;
  bf16* Kh = (bf16*)carve(26214400);        // [32][2048][200]
  bf16* Vt = (bf16*)carve(18874368);        // [32][32][128][72]

  if (used > ws_size) return;  // workspace too small: fail cleanly, no OOB writes

  cast_bf16<<<8192, 256, 0, stream>>>(hidden, Xb, 2097152);
  transpose_cast<<<dim3(96, 64), dim3(32, 8), 0, stream>>>(W_q, Wqkva_t, 2048, 3072, 3072);
  transpose_cast<<<dim3(20, 64), dim3(32, 8), 0, stream>>>(W_kva, Wqkva_t + (size_t)3072 * 2048,
                                                           2048, 576, 640);
  transpose_cast<<<dim3(128, 16), dim3(32, 8), 0, stream>>>(W_kvb, Wkvb_t, 512, 4096, 4096);
  transpose_cast<<<dim3(64, 64), dim3(32, 8), 0, stream>>>(W_o, Wo_t, 2048, 2048, 2048);

  // fused Q + KVA projection: [4096 x 3712] = Xb @ [Wq | Wkva]  (gemm2, GBM=16, GBN=29)
  gemm2_bt<bf16><<<16 * 29, 512, 0, stream>>>(Xb, Wqkva_t, QKVb, 4096, 3712, 2048, 16, 29);
  ln_rope<<<4096, 256, 0, stream>>>(QKVb, g, bta, pos, cosT, sinT, LNout, KPE);
  gemm2_bt<bf16><<<16 * 32, 512, 0, stream>>>(LNout, Wkvb_t, KVb, 4096, 4096, 512, 16, 32);
  pack_k<<<dim3(16, 4096), 64, 0, stream>>>(KVb, KPE, Kh);
  transpose_v<<<dim3(32, 64, 4), dim3(32, 8), 0, stream>>>(KVb, Vt);
  flash_attn<<<dim3(32, 32), 256, 0, stream>>>(QKVb, pos, cosT, sinT, Kh, Vt, Ob);
  // W_o applied twice: 64x128 tile (1024 blocks = 4/CU) + XCD-pinned grouping
  gemm64_bt<bf16><<<64 * 16, 256, 0, stream>>>(Ob, Wo_t, T1b, 4096, 2048, 2048, 16);
  gemm64_bt<float><<<64 * 16, 256, 0, stream>>>(T1b, Wo_t, out, 4096, 2048, 2048, 16);
}

// Round 21
// 352.241 us; speedup vs baseline: 1.0468x; 1.0468x over previous
//
#include <hip/hip_runtime.h>

// ---------- types ----------
typedef __bf16 bf16;
typedef __bf16 bf16x4 __attribute__((ext_vector_type(4)));
typedef __bf16 bf16x8 __attribute__((ext_vector_type(8)));
typedef float  f32x4  __attribute__((ext_vector_type(4)));

__device__ __forceinline__ f32x4 mfma16(bf16x8 a, bf16x8 b, f32x4 c) {
  return __builtin_amdgcn_mfma_f32_16x16x32_bf16(a, b, c, 0, 0, 0);
}
// global -> LDS async copy, 16B per lane. LDS ptr must be wave-uniform base
// (HW adds lane*16); global ptr is per-lane.
__device__ __forceinline__ void load_lds16(const void* g, void* l) {
  __builtin_amdgcn_global_load_lds((__attribute__((address_space(1))) void*)(g),
                                   (__attribute__((address_space(3))) void*)(l),
                                   16, 0, 0);
}

// ---------- elementwise casts ----------
__global__ void cast_bf16(const float* __restrict__ s, bf16* __restrict__ d, int n4) {
  int i = blockIdx.x * blockDim.x + threadIdx.x;
  if (i < n4) {
    float4 v = ((const float4*)s)[i];
    bf16x4 o = { (bf16)v.x, (bf16)v.y, (bf16)v.z, (bf16)v.w };
    *(bf16x4*)(d + (size_t)i * 4) = o;
  }
}

// src[K][N] f32 -> dst[Npad][K] bf16 (rows >= N zeroed)
__global__ void transpose_cast(const float* __restrict__ src, bf16* __restrict__ dst,
                               int K, int N, int Npad) {
  __shared__ float tile[32][33];
  const int n0 = blockIdx.x * 32, k0 = blockIdx.y * 32;
  const int tx = threadIdx.x, ty = threadIdx.y;
#pragma unroll
  for (int i = 0; i < 4; ++i) {
    int k = k0 + ty + i * 8, n = n0 + tx;
    tile[ty + i * 8][tx] = (k < K && n < N) ? src[(size_t)k * N + n] : 0.f;
  }
  __syncthreads();
#pragma unroll
  for (int i = 0; i < 4; ++i) {
    int n = n0 + ty + i * 8, k = k0 + tx;
    if (n < Npad && k < K) dst[(size_t)n * K + k] = (bf16)tile[tx][ty + i * 8];
  }
}

// ---------- GEMM v2 (large-K GEMMs: QKV, KVB): BM=256, BN=128, BK=32 ----------
// 512 threads = 8 waves (4M x 2N), dbuf LDS (48KB -> 3 blocks/CU), stage(t+1)
// issued before compute(t), one barrier per K-step. GROUP_M=8 ordering.
template <typename OutT>
__global__ __launch_bounds__(512) void gemm2_bt(
    const bf16* __restrict__ A, const bf16* __restrict__ Bt, OutT* __restrict__ C,
    int M, int N, int K, int GBM, int GBN) {
  __shared__ alignas(16) bf16 As[2][256 * 32];  // 16KB each
  __shared__ alignas(16) bf16 Bs[2][128 * 32];  //  8KB each
  const int wg = blockIdx.x;
  const int gsz = 8 * GBN;
  const int g = wg / gsz, rem = wg % gsz;
  const int bm = g * 8 + (rem % 8);
  const int bn = rem / 8;

  const int tid = threadIdx.x, wid = tid >> 6, lane = tid & 63;
  const int wr = wid >> 1, wc = wid & 1;  // wave grid 4(M) x 2(N)
  const int lo = lane & 15, hi = lane >> 4;
  const int w64 = wid * 64;

  f32x4 acc[4][4];
#pragma unroll
  for (int m = 0; m < 4; ++m)
#pragma unroll
    for (int n = 0; n < 4; ++n) acc[m][n] = f32x4{0.f, 0.f, 0.f, 0.f};

  const bf16* Abase = A + (size_t)(bm * 256) * K;
  const bf16* Bbase = Bt + (size_t)(bn * 128) * K;

  auto stage = [&](int buf, int kt) {
    int c = w64 + lane;
    load_lds16(Abase + (size_t)(c >> 2) * K + kt + (c & 3) * 8,
               &As[buf][0] + (size_t)w64 * 8);
    int c2 = 512 + w64 + lane;
    load_lds16(Abase + (size_t)(c2 >> 2) * K + kt + (c2 & 3) * 8,
               &As[buf][0] + (size_t)(512 + w64) * 8);
    load_lds16(Bbase + (size_t)(c >> 2) * K + kt + (c & 3) * 8,
               &Bs[buf][0] + (size_t)w64 * 8);
  };

  const int nt = K >> 5;
  stage(0, 0);
  __syncthreads();
  int cur = 0;
  for (int t = 0; t < nt; ++t) {
    if (t + 1 < nt) stage(cur ^ 1, (t + 1) << 5);  // issue prefetch FIRST
    bf16x8 af[4], bfr[4];
#pragma unroll
    for (int m = 0; m < 4; ++m)
      af[m] = *(const bf16x8*)(&As[cur][0] + (size_t)(wr * 64 + m * 16 + lo) * 32 + hi * 8);
#pragma unroll
    for (int n = 0; n < 4; ++n)
      bfr[n] = *(const bf16x8*)(&Bs[cur][0] + (size_t)(wc * 64 + n * 16 + lo) * 32 + hi * 8);
#pragma unroll
    for (int m = 0; m < 4; ++m)
#pragma unroll
      for (int n = 0; n < 4; ++n) acc[m][n] = mfma16(af[m], bfr[n], acc[m][n]);
    __syncthreads();  // drains prefetch DMA; guards buffer reuse
    cur ^= 1;
  }
#pragma unroll
  for (int m = 0; m < 4; ++m)
#pragma unroll
    for (int n = 0; n < 4; ++n)
#pragma unroll
      for (int r = 0; r < 4; ++r) {
        int row = bm * 256 + wr * 64 + m * 16 + hi * 4 + r;
        int col = bn * 128 + wc * 64 + n * 16 + lo;
        C[(size_t)row * N + col] = (OutT)acc[m][n][r];
      }
}

// ---------- GEMM 128² (Wo GEMMs only) + GROUP_M=8 XCD pinning ----------
template <typename OutT>
__global__ __launch_bounds__(256) void gemm1g_bt(
    const bf16* __restrict__ A, const bf16* __restrict__ Bt, OutT* __restrict__ C,
    int M, int N, int K, int GBN) {
  __shared__ alignas(16) bf16 As[128 * 32];
  __shared__ alignas(16) bf16 Bs[128 * 32];
  const int wg = blockIdx.x;
  const int gsz = 8 * GBN;
  const int g = wg / gsz, rem = wg % gsz;
  const int bm = g * 8 + (rem & 7);  // XCD (wg%8) <-> fixed bm within group
  const int bn = rem >> 3;
  const int tid = threadIdx.x, wid = tid >> 6, lane = tid & 63;
  const int wr = wid >> 1, wc = wid & 1;
  const int lo = lane & 15, hi = lane >> 4;
  f32x4 acc[4][4];
#pragma unroll
  for (int m = 0; m < 4; ++m)
#pragma unroll
    for (int n = 0; n < 4; ++n) acc[m][n] = f32x4{0.f, 0.f, 0.f, 0.f};

  const bf16* Abase = A + (size_t)(bm * 128) * K;
  const bf16* Bbase = Bt + (size_t)(bn * 128) * K;

  for (int kt = 0; kt < K; kt += 32) {
    __syncthreads();
    for (int c0 = wid * 64; c0 < 512; c0 += 256) {
      int c = c0 + lane;
      int row = c >> 2, kc = c & 3;
      load_lds16(Abase + (size_t)row * K + kt + kc * 8, As + (size_t)c0 * 8);
      load_lds16(Bbase + (size_t)row * K + kt + kc * 8, Bs + (size_t)c0 * 8);
    }
    __syncthreads();
    bf16x8 af[4], bfr[4];
#pragma unroll
    for (int m = 0; m < 4; ++m)
      af[m] = *(const bf16x8*)(As + (size_t)(wr * 64 + m * 16 + lo) * 32 + hi * 8);
#pragma unroll
    for (int n = 0; n < 4; ++n)
      bfr[n] = *(const bf16x8*)(Bs + (size_t)(wc * 64 + n * 16 + lo) * 32 + hi * 8);
#pragma unroll
    for (int m = 0; m < 4; ++m)
#pragma unroll
      for (int n = 0; n < 4; ++n) acc[m][n] = mfma16(af[m], bfr[n], acc[m][n]);
  }
#pragma unroll
  for (int m = 0; m < 4; ++m)
#pragma unroll
    for (int n = 0; n < 4; ++n)
#pragma unroll
      for (int r = 0; r < 4; ++r) {
        int row = bm * 128 + wr * 64 + m * 16 + hi * 4 + r;
        int col = bn * 128 + wc * 64 + n * 16 + lo;
        C[(size_t)row * N + col] = (OutT)acc[m][n][r];
      }
}

// ---------- LayerNorm(512) + RoPE on k_pe (ckv/k_pe read as bf16 from QKVb) ----
__global__ __launch_bounds__(256) void ln_rope(
    const bf16* __restrict__ QKVb, const float* __restrict__ g, const float* __restrict__ bta,
    const int* __restrict__ pos, const float* __restrict__ cosT, const float* __restrict__ sinT,
    bf16* __restrict__ LNout, float* __restrict__ KPE) {
  const int row = blockIdx.x, tid = threadIdx.x;
  const bf16* x = QKVb + (size_t)row * 3712 + 3072;
  float v0 = (float)x[tid], v1 = (float)x[tid + 256];
  float s = v0 + v1, s2 = v0 * v0 + v1 * v1;
#pragma unroll
  for (int off = 1; off < 64; off <<= 1) {
    s += __shfl_xor(s, off, 64);
    s2 += __shfl_xor(s2, off, 64);
  }
  __shared__ float red[8];
  const int wid = tid >> 6;
  if ((tid & 63) == 0) { red[wid] = s; red[4 + wid] = s2; }
  __syncthreads();
  s = red[0] + red[1] + red[2] + red[3];
  s2 = red[4] + red[5] + red[6] + red[7];
  const float mu = s * (1.f / 512.f);
  const float var = s2 * (1.f / 512.f) - mu * mu;
  const float rstd = rsqrtf(var + 1e-6f);
  LNout[(size_t)row * 512 + tid] = (bf16)((v0 - mu) * rstd * g[tid] + bta[tid]);
  LNout[(size_t)row * 512 + tid + 256] = (bf16)((v1 - mu) * rstd * g[tid + 256] + bta[tid + 256]);
  if (tid < 64) {
    float kvp = (float)x[512 + tid];
    float partner = (float)x[512 + (tid ^ 32)];
    float rot = (tid < 32) ? -partner : partner;
    int p = pos[row];
    KPE[(size_t)row * 64 + tid] = kvp * cosT[p * 64 + tid] + rot * sinT[p * 64 + tid];
  }
}

// ---------- pack K: [b][h][s][200] (rows padded 192->200, pad zeroed) ----------
__global__ void pack_k(const bf16* __restrict__ KVb, const float* __restrict__ KPE,
                       bf16* __restrict__ Kh) {
  const int h = blockIdx.x, row = blockIdx.y;
  const int t = threadIdx.x;
  const bf16* kv = KVb + (size_t)row * 4096 + h * 256;
  bf16* o = Kh + ((size_t)((row >> 11) * 16 + h) * 2048 + (row & 2047)) * 200;
  o[t] = kv[t];
  o[t + 64] = kv[t + 64];
  o[128 + t] = (bf16)KPE[(size_t)row * 64 + t];
  if (t < 8) o[192 + t] = (bf16)0.f;
}

// ---------- V transpose: [b][h][kv_tile][128 d][72 kv] (pad zeroed) ----------
__global__ void transpose_v(const bf16* __restrict__ KVb, bf16* __restrict__ Vt) {
  __shared__ bf16 tile[32][33];
  const int bh = blockIdx.x, st = blockIdx.y, dt = blockIdx.z;
  const int b = bh >> 4, h = bh & 15;
  const int tx = threadIdx.x, ty = threadIdx.y;
#pragma unroll
  for (int i = 0; i < 4; ++i) {
    int sIdx = st * 32 + ty + i * 8;
    tile[ty + i * 8][tx] = KVb[(size_t)(b * 2048 + sIdx) * 4096 + h * 256 + 128 + dt * 32 + tx];
  }
  __syncthreads();
  const int kt = st >> 1;
  const int kvl = (st & 1) * 32;
#pragma unroll
  for (int i = 0; i < 4; ++i) {
    int d = dt * 32 + ty + i * 8;
    size_t rowbase = ((size_t)(bh * 32 + kt) * 128 + d) * 72;
    Vt[rowbase + kvl + tx] = tile[tx][ty + i * 8];
    if ((st & 1) && tx < 8) Vt[rowbase + 64 + tx] = (bf16)0.f;
  }
}

// ---------- flash attention (causal) v6 + fused Q-RoPE prologue ----------
// Measured optimum of this structure family (r13/r19: ~107us). 52 KiB LDS ->
// 3 blocks/CU; ones-MFMA rowsum; setprio around MFMA clusters; LPT qt order.
__global__ __launch_bounds__(256, 3) void flash_attn(
    const bf16* __restrict__ QKVb, const int* __restrict__ pos,
    const float* __restrict__ cosT, const float* __restrict__ sinT,
    const bf16* __restrict__ Kh, const bf16* __restrict__ Vt,
    bf16* __restrict__ Ob) {
  __shared__ alignas(16) bf16 Ks[64 * 200];   // 25600 B
  __shared__ alignas(16) bf16 Vs[128 * 72];   // 18432 B
  __shared__ alignas(16) bf16 Ps[4][16 * 72]; //  9216 B
  const int bh = blockIdx.x, qt = 31 - blockIdx.y;  // longest blocks first
  const int b = bh >> 4, h = bh & 15;
  const int tid = threadIdx.x, wid = tid >> 6, lane = tid & 63;
  const int lo = lane & 15, hi = lane >> 4;
  const int q0 = qt * 64 + wid * 16;

  bf16x8 qf[6];
  {
    const int grow_i = b * 2048 + q0 + lo;
    const bf16* qsrc = QKVb + (size_t)grow_i * 3712 + h * 192 + hi * 8;
    bf16x8 raw[6];
#pragma unroll
    for (int kg = 0; kg < 6; ++kg) raw[kg] = *(const bf16x8*)(qsrc + kg * 32);
    const float scale = 0.07216878364870322f;  // 1/sqrt(192)
#pragma unroll
    for (int kg = 0; kg < 4; ++kg)
#pragma unroll
      for (int j = 0; j < 8; ++j) qf[kg][j] = (bf16)((float)raw[kg][j] * scale);
    const int p = pos[grow_i];
    const float* cb = cosT + p * 64 + hi * 8;
    const float* sb = sinT + p * 64 + hi * 8;
#pragma unroll
    for (int j = 0; j < 8; ++j) {
      float q4 = (float)raw[4][j], q5 = (float)raw[5][j];
      qf[4][j] = (bf16)((q4 * cb[j] - q5 * sb[j]) * scale);            // d<32: rot=-partner
      qf[5][j] = (bf16)((q5 * cb[32 + j] + q4 * sb[32 + j]) * scale);  // d>=32: rot=+partner
    }
  }
  float m_r[4] = {-INFINITY, -INFINITY, -INFINITY, -INFINITY};
  f32x4 accl = f32x4{0.f, 0.f, 0.f, 0.f};  // row-sum accumulator (l), D-layout
  f32x4 acc[8];
#pragma unroll
  for (int v = 0; v < 8; ++v) acc[v] = f32x4{0.f, 0.f, 0.f, 0.f};
  const bf16 one_b = (bf16)1.f;
  const bf16x8 ones = {one_b, one_b, one_b, one_b, one_b, one_b, one_b, one_b};

  const bf16* Kbase = Kh + (size_t)bh * 2048 * 200;
  const bf16* Vbase = Vt + (size_t)bh * 32 * (128 * 72);
  bf16* Pw = &Ps[wid][0];

  const int last = qt * 64;
  for (int kv0 = 0; kv0 <= last; kv0 += 64) {
    // stage K(t) + V(t); buffers free per barrier #2 of previous iter
    {
      const bf16* srcK = Kbase + (size_t)kv0 * 200;
      for (int c0 = wid * 64; c0 < 1600; c0 += 256)
        load_lds16(srcK + (size_t)(c0 + lane) * 8, Ks + (size_t)c0 * 8);
      const bf16* srcV = Vbase + (size_t)(kv0 >> 6) * (128 * 72);
      for (int c0 = wid * 64; c0 < 1152; c0 += 256)
        load_lds16(srcV + (size_t)(c0 + lane) * 8, Vs + (size_t)c0 * 8);
    }
    __syncthreads();  // #1: drain DMA (vmcnt0)

    // S = Q K^T  (per wave: 16 q x 64 kv)
    f32x4 sacc[4];
    __builtin_amdgcn_s_setprio(1);
#pragma unroll
    for (int nk = 0; nk < 4; ++nk) {
      sacc[nk] = f32x4{0.f, 0.f, 0.f, 0.f};
#pragma unroll
      for (int kg = 0; kg < 6; ++kg) {
        bf16x8 kf = *(const bf16x8*)(Ks + (size_t)(nk * 16 + lo) * 200 + kg * 32 + hi * 8);
        sacc[nk] = mfma16(qf[kg], kf, sacc[nk]);
      }
    }
    __builtin_amdgcn_s_setprio(0);
    if (kv0 == last) {  // diagonal tile: causal mask
#pragma unroll
      for (int nk = 0; nk < 4; ++nk)
#pragma unroll
        for (int r = 0; r < 4; ++r)
          if (kv0 + nk * 16 + lo > q0 + hi * 4 + r) sacc[nk][r] = -INFINITY;
    }
    // online softmax: max-reduce only (sum via ones-MFMA)
    float sc[4];
#pragma unroll
    for (int r = 0; r < 4; ++r) {
      float mx = fmaxf(fmaxf(sacc[0][r], sacc[1][r]), fmaxf(sacc[2][r], sacc[3][r]));
      mx = fmaxf(mx, __shfl_xor(mx, 1, 64));
      mx = fmaxf(mx, __shfl_xor(mx, 2, 64));
      mx = fmaxf(mx, __shfl_xor(mx, 4, 64));
      mx = fmaxf(mx, __shfl_xor(mx, 8, 64));
      float mnew = fmaxf(m_r[r], mx);
      sc[r] = __expf(m_r[r] - mnew);
      m_r[r] = mnew;
    }
#pragma unroll
    for (int nk = 0; nk < 4; ++nk)
#pragma unroll
      for (int r = 0; r < 4; ++r) {
        float p = __expf(sacc[nk][r] - m_r[r]);
        Pw[(hi * 4 + r) * 72 + nk * 16 + lo] = (bf16)p;
      }
#pragma unroll
    for (int r = 0; r < 4; ++r) {
      accl[r] *= sc[r];
#pragma unroll
      for (int v = 0; v < 8; ++v) acc[v][r] *= sc[r];
    }
    // P fragments (own-wave region; same-wave RAW via lgkmcnt, no barrier)
    bf16x8 pf0 = *(const bf16x8*)(Pw + (size_t)lo * 72 + hi * 8);
    bf16x8 pf1 = *(const bf16x8*)(Pw + (size_t)lo * 72 + 32 + hi * 8);
    __builtin_amdgcn_s_setprio(1);
    accl = mfma16(pf0, ones, accl);
    accl = mfma16(pf1, ones, accl);
    // PV: P (16 x 64) @ V (64 x 128); Vs holds V^T [d][kv]
#pragma unroll
    for (int v = 0; v < 8; ++v) {
      const bf16* vrow = Vs + (size_t)(v * 16 + lo) * 72 + hi * 8;
      bf16x8 vf0 = *(const bf16x8*)(vrow);
      bf16x8 vf1 = *(const bf16x8*)(vrow + 32);
      acc[v] = mfma16(pf0, vf0, acc[v]);
      acc[v] = mfma16(pf1, vf1, acc[v]);
    }
    __builtin_amdgcn_s_setprio(0);
    __syncthreads();  // #2: all K/V/P reads done before next tile's stage
  }
  // epilogue: O /= l, write bf16 to Ob[b][q][h*128+d]
#pragma unroll
  for (int r = 0; r < 4; ++r) {
    float invl = 1.f / accl[r];
    int qrow = q0 + hi * 4 + r;
    bf16* orow = Ob + ((size_t)b * 2048 + qrow) * 2048 + h * 128 + lo;
#pragma unroll
    for (int v = 0; v < 8; ++v) orow[v * 16] = (bf16)(acc[v][r] * invl);
  }
}

// ---------- launcher ----------
extern "C" void kernel_launch(void* const* d_in, const int* in_sizes, int n_in,
                              void* d_out, int out_size, void* d_ws, size_t ws_size,
                              hipStream_t stream) {
  const float* hidden = (const float*)d_in[0];
  const int* pos = (const int*)d_in[1];
  const float* cosT = (const float*)d_in[2];
  const float* sinT = (const float*)d_in[3];
  const float* W_q = (const float*)d_in[4];
  const float* W_kva = (const float*)d_in[5];
  const float* g = (const float*)d_in[6];
  const float* bta = (const float*)d_in[7];
  const float* W_kvb = (const float*)d_in[8];
  const float* W_o = (const float*)d_in[9];
  float* out = (float*)d_out;

  char* w = (char*)d_ws;
  size_t used = 0;
  auto carve = [&](size_t bytes) -> char* {
    char* p = w;
    size_t pad = (bytes + 255) & ~(size_t)255;
    w += pad;
    used += pad;
    return p;
  };
  bf16* Xb = (bf16*)carve(16777216);        // [4096][2048]
  bf16* Wqkva_t = (bf16*)carve(15204352);   // [3712][2048]: Wq rows 0..3071, Wkva rows 3072..3711
  bf16* Wkvb_t = (bf16*)carve(4194304);     // [4096][512]
  bf16* Wo_t = (bf16*)carve(8388608);       // [2048][2048]
  bf16* QKVb = (bf16*)carve(30408704);      // [4096][3712] (read by flash_attn; NOT aliased)
  bf16* Ob = (bf16*)carve(16777216);        // [4096][2048] dedicated
  bf16* LNout = (bf16*)carve(4194304);      // [4096][512]
  float* KPE = (float*)carve(1048576);      // [4096][64] f32
  char* KVT1 = carve(33554432);             // KVb [4096][4096]; reused as T1b [4096][2048]
  bf16* KVb = (bf16*)KVT1;
  bf16* T1b = (bf16*)KVT1;
  bf16* Kh = (bf16*)carve(26214400);        // [32][2048][200]
  bf16* Vt = (bf16*)carve(18874368);        // [32][32][128][72]

  if (used > ws_size) return;  // workspace too small: fail cleanly, no OOB writes

  cast_bf16<<<8192, 256, 0, stream>>>(hidden, Xb, 2097152);
  transpose_cast<<<dim3(96, 64), dim3(32, 8), 0, stream>>>(W_q, Wqkva_t, 2048, 3072, 3072);
  transpose_cast<<<dim3(20, 64), dim3(32, 8), 0, stream>>>(W_kva, Wqkva_t + (size_t)3072 * 2048,
                                                           2048, 576, 640);
  transpose_cast<<<dim3(128, 16), dim3(32, 8), 0, stream>>>(W_kvb, Wkvb_t, 512, 4096, 4096);
  transpose_cast<<<dim3(64, 64), dim3(32, 8), 0, stream>>>(W_o, Wo_t, 2048, 2048, 2048);

  // fused Q + KVA projection: [4096 x 3712] = Xb @ [Wq | Wkva]  (gemm2, GBM=16, GBN=29)
  gemm2_bt<bf16><<<16 * 29, 512, 0, stream>>>(Xb, Wqkva_t, QKVb, 4096, 3712, 2048, 16, 29);
  ln_rope<<<4096, 256, 0, stream>>>(QKVb, g, bta, pos, cosT, sinT, LNout, KPE);
  gemm2_bt<bf16><<<16 * 32, 512, 0, stream>>>(LNout, Wkvb_t, KVb, 4096, 4096, 512, 16, 32);
  pack_k<<<dim3(16, 4096), 64, 0, stream>>>(KVb, KPE, Kh);
  transpose_v<<<dim3(32, 64, 4), dim3(32, 8), 0, stream>>>(KVb, Vt);
  flash_attn<<<dim3(32, 32), 256, 0, stream>>>(QKVb, pos, cosT, sinT, Kh, Vt, Ob);
  // W_o applied twice: 128² m97 structure + XCD-pinned grouping (GBN=16)
  gemm1g_bt<bf16><<<32 * 16, 256, 0, stream>>>(Ob, Wo_t, T1b, 4096, 2048, 2048, 16);
  gemm1g_bt<float><<<32 * 16, 256, 0, stream>>>(T1b, Wo_t, out, 4096, 2048, 2048, 16);
}

// Round 22
// 346.539 us; speedup vs baseline: 1.0640x; 1.0165x over previous
//
#include <hip/hip_runtime.h>

// ---------- types ----------
typedef __bf16 bf16;
typedef __bf16 bf16x4 __attribute__((ext_vector_type(4)));
typedef __bf16 bf16x8 __attribute__((ext_vector_type(8)));
typedef float  f32x4  __attribute__((ext_vector_type(4)));

__device__ __forceinline__ f32x4 mfma16(bf16x8 a, bf16x8 b, f32x4 c) {
  return __builtin_amdgcn_mfma_f32_16x16x32_bf16(a, b, c, 0, 0, 0);
}
// global -> LDS async copy, 16B per lane. LDS ptr must be wave-uniform base
// (HW adds lane*16); GLOBAL ptr is per-lane (enables gather-staging).
__device__ __forceinline__ void load_lds16(const void* g, void* l) {
  __builtin_amdgcn_global_load_lds((__attribute__((address_space(1))) void*)(g),
                                   (__attribute__((address_space(3))) void*)(l),
                                   16, 0, 0);
}

// ---------- elementwise casts ----------
__global__ void cast_bf16(const float* __restrict__ s, bf16* __restrict__ d, int n4) {
  int i = blockIdx.x * blockDim.x + threadIdx.x;
  if (i < n4) {
    float4 v = ((const float4*)s)[i];
    bf16x4 o = { (bf16)v.x, (bf16)v.y, (bf16)v.z, (bf16)v.w };
    *(bf16x4*)(d + (size_t)i * 4) = o;
  }
}

// src[K][N] f32 -> dst[Npad][K] bf16 (rows >= N zeroed)
__global__ void transpose_cast(const float* __restrict__ src, bf16* __restrict__ dst,
                               int K, int N, int Npad) {
  __shared__ float tile[32][33];
  const int n0 = blockIdx.x * 32, k0 = blockIdx.y * 32;
  const int tx = threadIdx.x, ty = threadIdx.y;
#pragma unroll
  for (int i = 0; i < 4; ++i) {
    int k = k0 + ty + i * 8, n = n0 + tx;
    tile[ty + i * 8][tx] = (k < K && n < N) ? src[(size_t)k * N + n] : 0.f;
  }
  __syncthreads();
#pragma unroll
  for (int i = 0; i < 4; ++i) {
    int n = n0 + ty + i * 8, k = k0 + tx;
    if (n < Npad && k < K) dst[(size_t)n * K + k] = (bf16)tile[tx][ty + i * 8];
  }
}

// ---------- GEMM v2 (large-K GEMMs: QKV, KVB): BM=256, BN=128, BK=32 ----------
// 512 threads = 8 waves (4M x 2N), dbuf LDS (48KB -> 3 blocks/CU), stage(t+1)
// issued before compute(t), one barrier per K-step. GROUP_M=8 ordering.
template <typename OutT>
__global__ __launch_bounds__(512) void gemm2_bt(
    const bf16* __restrict__ A, const bf16* __restrict__ Bt, OutT* __restrict__ C,
    int M, int N, int K, int GBM, int GBN) {
  __shared__ alignas(16) bf16 As[2][256 * 32];  // 16KB each
  __shared__ alignas(16) bf16 Bs[2][128 * 32];  //  8KB each
  const int wg = blockIdx.x;
  const int gsz = 8 * GBN;
  const int g = wg / gsz, rem = wg % gsz;
  const int bm = g * 8 + (rem % 8);
  const int bn = rem / 8;

  const int tid = threadIdx.x, wid = tid >> 6, lane = tid & 63;
  const int wr = wid >> 1, wc = wid & 1;  // wave grid 4(M) x 2(N)
  const int lo = lane & 15, hi = lane >> 4;
  const int w64 = wid * 64;

  f32x4 acc[4][4];
#pragma unroll
  for (int m = 0; m < 4; ++m)
#pragma unroll
    for (int n = 0; n < 4; ++n) acc[m][n] = f32x4{0.f, 0.f, 0.f, 0.f};

  const bf16* Abase = A + (size_t)(bm * 256) * K;
  const bf16* Bbase = Bt + (size_t)(bn * 128) * K;

  auto stage = [&](int buf, int kt) {
    int c = w64 + lane;
    load_lds16(Abase + (size_t)(c >> 2) * K + kt + (c & 3) * 8,
               &As[buf][0] + (size_t)w64 * 8);
    int c2 = 512 + w64 + lane;
    load_lds16(Abase + (size_t)(c2 >> 2) * K + kt + (c2 & 3) * 8,
               &As[buf][0] + (size_t)(512 + w64) * 8);
    load_lds16(Bbase + (size_t)(c >> 2) * K + kt + (c & 3) * 8,
               &Bs[buf][0] + (size_t)w64 * 8);
  };

  const int nt = K >> 5;
  stage(0, 0);
  __syncthreads();
  int cur = 0;
  for (int t = 0; t < nt; ++t) {
    if (t + 1 < nt) stage(cur ^ 1, (t + 1) << 5);  // issue prefetch FIRST
    bf16x8 af[4], bfr[4];
#pragma unroll
    for (int m = 0; m < 4; ++m)
      af[m] = *(const bf16x8*)(&As[cur][0] + (size_t)(wr * 64 + m * 16 + lo) * 32 + hi * 8);
#pragma unroll
    for (int n = 0; n < 4; ++n)
      bfr[n] = *(const bf16x8*)(&Bs[cur][0] + (size_t)(wc * 64 + n * 16 + lo) * 32 + hi * 8);
#pragma unroll
    for (int m = 0; m < 4; ++m)
#pragma unroll
      for (int n = 0; n < 4; ++n) acc[m][n] = mfma16(af[m], bfr[n], acc[m][n]);
    __syncthreads();  // drains prefetch DMA; guards buffer reuse
    cur ^= 1;
  }
#pragma unroll
  for (int m = 0; m < 4; ++m)
#pragma unroll
    for (int n = 0; n < 4; ++n)
#pragma unroll
      for (int r = 0; r < 4; ++r) {
        int row = bm * 256 + wr * 64 + m * 16 + hi * 4 + r;
        int col = bn * 128 + wc * 64 + n * 16 + lo;
        C[(size_t)row * N + col] = (OutT)acc[m][n][r];
      }
}

// ---------- GEMM 128² (Wo GEMMs only) + GROUP_M=8 XCD pinning ----------
template <typename OutT>
__global__ __launch_bounds__(256) void gemm1g_bt(
    const bf16* __restrict__ A, const bf16* __restrict__ Bt, OutT* __restrict__ C,
    int M, int N, int K, int GBN) {
  __shared__ alignas(16) bf16 As[128 * 32];
  __shared__ alignas(16) bf16 Bs[128 * 32];
  const int wg = blockIdx.x;
  const int gsz = 8 * GBN;
  const int g = wg / gsz, rem = wg % gsz;
  const int bm = g * 8 + (rem & 7);  // XCD (wg%8) <-> fixed bm within group
  const int bn = rem >> 3;
  const int tid = threadIdx.x, wid = tid >> 6, lane = tid & 63;
  const int wr = wid >> 1, wc = wid & 1;
  const int lo = lane & 15, hi = lane >> 4;
  f32x4 acc[4][4];
#pragma unroll
  for (int m = 0; m < 4; ++m)
#pragma unroll
    for (int n = 0; n < 4; ++n) acc[m][n] = f32x4{0.f, 0.f, 0.f, 0.f};

  const bf16* Abase = A + (size_t)(bm * 128) * K;
  const bf16* Bbase = Bt + (size_t)(bn * 128) * K;

  for (int kt = 0; kt < K; kt += 32) {
    __syncthreads();
    for (int c0 = wid * 64; c0 < 512; c0 += 256) {
      int c = c0 + lane;
      int row = c >> 2, kc = c & 3;
      load_lds16(Abase + (size_t)row * K + kt + kc * 8, As + (size_t)c0 * 8);
      load_lds16(Bbase + (size_t)row * K + kt + kc * 8, Bs + (size_t)c0 * 8);
    }
    __syncthreads();
    bf16x8 af[4], bfr[4];
#pragma unroll
    for (int m = 0; m < 4; ++m)
      af[m] = *(const bf16x8*)(As + (size_t)(wr * 64 + m * 16 + lo) * 32 + hi * 8);
#pragma unroll
    for (int n = 0; n < 4; ++n)
      bfr[n] = *(const bf16x8*)(Bs + (size_t)(wc * 64 + n * 16 + lo) * 32 + hi * 8);
#pragma unroll
    for (int m = 0; m < 4; ++m)
#pragma unroll
      for (int n = 0; n < 4; ++n) acc[m][n] = mfma16(af[m], bfr[n], acc[m][n]);
  }
#pragma unroll
  for (int m = 0; m < 4; ++m)
#pragma unroll
    for (int n = 0; n < 4; ++n)
#pragma unroll
      for (int r = 0; r < 4; ++r) {
        int row = bm * 128 + wr * 64 + m * 16 + hi * 4 + r;
        int col = bn * 128 + wc * 64 + n * 16 + lo;
        C[(size_t)row * N + col] = (OutT)acc[m][n][r];
      }
}

// ---------- LayerNorm(512) + RoPE on k_pe; KPE written as bf16 ----------
__global__ __launch_bounds__(256) void ln_rope(
    const bf16* __restrict__ QKVb, const float* __restrict__ g, const float* __restrict__ bta,
    const int* __restrict__ pos, const float* __restrict__ cosT, const float* __restrict__ sinT,
    bf16* __restrict__ LNout, bf16* __restrict__ KPEb) {
  const int row = blockIdx.x, tid = threadIdx.x;
  const bf16* x = QKVb + (size_t)row * 3712 + 3072;
  float v0 = (float)x[tid], v1 = (float)x[tid + 256];
  float s = v0 + v1, s2 = v0 * v0 + v1 * v1;
#pragma unroll
  for (int off = 1; off < 64; off <<= 1) {
    s += __shfl_xor(s, off, 64);
    s2 += __shfl_xor(s2, off, 64);
  }
  __shared__ float red[8];
  const int wid = tid >> 6;
  if ((tid & 63) == 0) { red[wid] = s; red[4 + wid] = s2; }
  __syncthreads();
  s = red[0] + red[1] + red[2] + red[3];
  s2 = red[4] + red[5] + red[6] + red[7];
  const float mu = s * (1.f / 512.f);
  const float var = s2 * (1.f / 512.f) - mu * mu;
  const float rstd = rsqrtf(var + 1e-6f);
  LNout[(size_t)row * 512 + tid] = (bf16)((v0 - mu) * rstd * g[tid] + bta[tid]);
  LNout[(size_t)row * 512 + tid + 256] = (bf16)((v1 - mu) * rstd * g[tid + 256] + bta[tid + 256]);
  if (tid < 64) {
    float kvp = (float)x[512 + tid];
    float partner = (float)x[512 + (tid ^ 32)];
    float rot = (tid < 32) ? -partner : partner;
    int p = pos[row];
    // same rounding path as before (pack_k cast KPE f32->bf16)
    KPEb[(size_t)row * 64 + tid] = (bf16)(kvp * cosT[p * 64 + tid] + rot * sinT[p * 64 + tid]);
  }
}

// ---------- V transpose: [b][h][kv_tile][128 d][72 kv] (pad zeroed) ----------
__global__ void transpose_v(const bf16* __restrict__ KVb, bf16* __restrict__ Vt) {
  __shared__ bf16 tile[32][33];
  const int bh = blockIdx.x, st = blockIdx.y, dt = blockIdx.z;
  const int b = bh >> 4, h = bh & 15;
  const int tx = threadIdx.x, ty = threadIdx.y;
#pragma unroll
  for (int i = 0; i < 4; ++i) {
    int sIdx = st * 32 + ty + i * 8;
    tile[ty + i * 8][tx] = KVb[(size_t)(b * 2048 + sIdx) * 4096 + h * 256 + 128 + dt * 32 + tx];
  }
  __syncthreads();
  const int kt = st >> 1;
  const int kvl = (st & 1) * 32;
#pragma unroll
  for (int i = 0; i < 4; ++i) {
    int d = dt * 32 + ty + i * 8;
    size_t rowbase = ((size_t)(bh * 32 + kt) * 128 + d) * 72;
    Vt[rowbase + kvl + tx] = tile[tx][ty + i * 8];
    if ((st & 1) && tx < 8) Vt[rowbase + 64 + tx] = (bf16)0.f;
  }
}

// ---------- flash attention (causal) v6 + fused Q-RoPE + gather-staged K ----
// K is staged directly from KVb (nope) + KPEb (rope'd pe) + zero stub (pad)
// via per-lane global addresses -> pack_k kernel and Kh buffer eliminated.
// LDS row layout identical ([64][200], chunk c -> row c/25, part c%25).
__global__ __launch_bounds__(256, 3) void flash_attn(
    const bf16* __restrict__ QKVb, const int* __restrict__ pos,
    const float* __restrict__ cosT, const float* __restrict__ sinT,
    const bf16* __restrict__ KVb, const bf16* __restrict__ KPEb,
    const bf16* __restrict__ zero16, const bf16* __restrict__ Vt,
    bf16* __restrict__ Ob) {
  __shared__ alignas(16) bf16 Ks[64 * 200];   // 25600 B
  __shared__ alignas(16) bf16 Vs[128 * 72];   // 18432 B
  __shared__ alignas(16) bf16 Ps[4][16 * 72]; //  9216 B
  const int bh = blockIdx.x, qt = 31 - blockIdx.y;  // longest blocks first
  const int b = bh >> 4, h = bh & 15;
  const int tid = threadIdx.x, wid = tid >> 6, lane = tid & 63;
  const int lo = lane & 15, hi = lane >> 4;
  const int q0 = qt * 64 + wid * 16;

  bf16x8 qf[6];
  {
    const int grow_i = b * 2048 + q0 + lo;
    const bf16* qsrc = QKVb + (size_t)grow_i * 3712 + h * 192 + hi * 8;
    bf16x8 raw[6];
#pragma unroll
    for (int kg = 0; kg < 6; ++kg) raw[kg] = *(const bf16x8*)(qsrc + kg * 32);
    const float scale = 0.07216878364870322f;  // 1/sqrt(192)
#pragma unroll
    for (int kg = 0; kg < 4; ++kg)
#pragma unroll
      for (int j = 0; j < 8; ++j) qf[kg][j] = (bf16)((float)raw[kg][j] * scale);
    const int p = pos[grow_i];
    const float* cb = cosT + p * 64 + hi * 8;
    const float* sb = sinT + p * 64 + hi * 8;
#pragma unroll
    for (int j = 0; j < 8; ++j) {
      float q4 = (float)raw[4][j], q5 = (float)raw[5][j];
      qf[4][j] = (bf16)((q4 * cb[j] - q5 * sb[j]) * scale);            // d<32: rot=-partner
      qf[5][j] = (bf16)((q5 * cb[32 + j] + q4 * sb[32 + j]) * scale);  // d>=32: rot=+partner
    }
  }
  float m_r[4] = {-INFINITY, -INFINITY, -INFINITY, -INFINITY};
  f32x4 accl = f32x4{0.f, 0.f, 0.f, 0.f};  // row-sum accumulator (l), D-layout
  f32x4 acc[8];
#pragma unroll
  for (int v = 0; v < 8; ++v) acc[v] = f32x4{0.f, 0.f, 0.f, 0.f};
  const bf16 one_b = (bf16)1.f;
  const bf16x8 ones = {one_b, one_b, one_b, one_b, one_b, one_b, one_b, one_b};

  // per-lane chunk decomposition for K gather-staging (done once)
  // chunk c = c0 + lane; row r = c/25, part p = c%25
  const bf16* KVbK = KVb + ((size_t)b * 2048) * 4096 + h * 256;  // + (kv0+r)*4096 + p*8
  const bf16* KPEbase = KPEb + ((size_t)b * 2048) * 64;          // + (kv0+r)*64 + (p-16)*8
  const bf16* Vbase = Vt + (size_t)bh * 32 * (128 * 72);
  bf16* Pw = &Ps[wid][0];

  const int last = qt * 64;
  for (int kv0 = 0; kv0 <= last; kv0 += 64) {
    // stage K(t) via gather (nope from KVb, pe from KPEb, pad from zero16)
    for (int c0 = wid * 64; c0 < 1600; c0 += 256) {
      unsigned c = c0 + lane;
      unsigned r = c / 25u;
      unsigned p = c - r * 25u;
      const bf16* aN = KVbK + (size_t)(kv0 + r) * 4096 + p * 8;
      const bf16* aP = KPEbase + (size_t)(kv0 + r) * 64 + ((int)p - 16) * 8;
      const bf16* src = (p < 16u) ? aN : ((p < 24u) ? aP : zero16);
      load_lds16(src, Ks + (size_t)c0 * 8);
    }
    // stage V(t) (linear copy, pre-transposed/padded)
    {
      const bf16* srcV = Vbase + (size_t)(kv0 >> 6) * (128 * 72);
      for (int c0 = wid * 64; c0 < 1152; c0 += 256)
        load_lds16(srcV + (size_t)(c0 + lane) * 8, Vs + (size_t)c0 * 8);
    }
    __syncthreads();  // #1: drain DMA (vmcnt0)

    // S = Q K^T  (per wave: 16 q x 64 kv)
    f32x4 sacc[4];
    __builtin_amdgcn_s_setprio(1);
#pragma unroll
    for (int nk = 0; nk < 4; ++nk) {
      sacc[nk] = f32x4{0.f, 0.f, 0.f, 0.f};
#pragma unroll
      for (int kg = 0; kg < 6; ++kg) {
        bf16x8 kf = *(const bf16x8*)(Ks + (size_t)(nk * 16 + lo) * 200 + kg * 32 + hi * 8);
        sacc[nk] = mfma16(qf[kg], kf, sacc[nk]);
      }
    }
    __builtin_amdgcn_s_setprio(0);
    if (kv0 == last) {  // diagonal tile: causal mask
#pragma unroll
      for (int nk = 0; nk < 4; ++nk)
#pragma unroll
        for (int r = 0; r < 4; ++r)
          if (kv0 + nk * 16 + lo > q0 + hi * 4 + r) sacc[nk][r] = -INFINITY;
    }
    // online softmax: max-reduce only (sum via ones-MFMA)
    float sc[4];
#pragma unroll
    for (int r = 0; r < 4; ++r) {
      float mx = fmaxf(fmaxf(sacc[0][r], sacc[1][r]), fmaxf(sacc[2][r], sacc[3][r]));
      mx = fmaxf(mx, __shfl_xor(mx, 1, 64));
      mx = fmaxf(mx, __shfl_xor(mx, 2, 64));
      mx = fmaxf(mx, __shfl_xor(mx, 4, 64));
      mx = fmaxf(mx, __shfl_xor(mx, 8, 64));
      float mnew = fmaxf(m_r[r], mx);
      sc[r] = __expf(m_r[r] - mnew);
      m_r[r] = mnew;
    }
#pragma unroll
    for (int nk = 0; nk < 4; ++nk)
#pragma unroll
      for (int r = 0; r < 4; ++r) {
        float p = __expf(sacc[nk][r] - m_r[r]);
        Pw[(hi * 4 + r) * 72 + nk * 16 + lo] = (bf16)p;
      }
#pragma unroll
    for (int r = 0; r < 4; ++r) {
      accl[r] *= sc[r];
#pragma unroll
      for (int v = 0; v < 8; ++v) acc[v][r] *= sc[r];
    }
    // P fragments (own-wave region; same-wave RAW via lgkmcnt, no barrier)
    bf16x8 pf0 = *(const bf16x8*)(Pw + (size_t)lo * 72 + hi * 8);
    bf16x8 pf1 = *(const bf16x8*)(Pw + (size_t)lo * 72 + 32 + hi * 8);
    __builtin_amdgcn_s_setprio(1);
    accl = mfma16(pf0, ones, accl);
    accl = mfma16(pf1, ones, accl);
    // PV: P (16 x 64) @ V (64 x 128); Vs holds V^T [d][kv]
#pragma unroll
    for (int v = 0; v < 8; ++v) {
      const bf16* vrow = Vs + (size_t)(v * 16 + lo) * 72 + hi * 8;
      bf16x8 vf0 = *(const bf16x8*)(vrow);
      bf16x8 vf1 = *(const bf16x8*)(vrow + 32);
      acc[v] = mfma16(pf0, vf0, acc[v]);
      acc[v] = mfma16(pf1, vf1, acc[v]);
    }
    __builtin_amdgcn_s_setprio(0);
    __syncthreads();  // #2: all K/V/P reads done before next tile's stage
  }
  // epilogue: O /= l, write bf16 to Ob[b][q][h*128+d]
#pragma unroll
  for (int r = 0; r < 4; ++r) {
    float invl = 1.f / accl[r];
    int qrow = q0 + hi * 4 + r;
    bf16* orow = Ob + ((size_t)b * 2048 + qrow) * 2048 + h * 128 + lo;
#pragma unroll
    for (int v = 0; v < 8; ++v) orow[v * 16] = (bf16)(acc[v][r] * invl);
  }
}

// ---------- launcher ----------
extern "C" void kernel_launch(void* const* d_in, const int* in_sizes, int n_in,
                              void* d_out, int out_size, void* d_ws, size_t ws_size,
                              hipStream_t stream) {
  const float* hidden = (const float*)d_in[0];
  const int* pos = (const int*)d_in[1];
  const float* cosT = (const float*)d_in[2];
  const float* sinT = (const float*)d_in[3];
  const float* W_q = (const float*)d_in[4];
  const float* W_kva = (const float*)d_in[5];
  const float* g = (const float*)d_in[6];
  const float* bta = (const float*)d_in[7];
  const float* W_kvb = (const float*)d_in[8];
  const float* W_o = (const float*)d_in[9];
  float* out = (float*)d_out;

  char* w = (char*)d_ws;
  size_t used = 0;
  auto carve = [&](size_t bytes) -> char* {
    char* p = w;
    size_t pad = (bytes + 255) & ~(size_t)255;
    w += pad;
    used += pad;
    return p;
  };
  bf16* Xb = (bf16*)carve(16777216);        // [4096][2048]
  bf16* Wqkva_t = (bf16*)carve(15204352);   // [3712][2048]: Wq rows 0..3071, Wkva rows 3072..3711
  bf16* Wkvb_t = (bf16*)carve(4194304);     // [4096][512]
  bf16* Wo_t = (bf16*)carve(8388608);       // [2048][2048]
  bf16* QKVb = (bf16*)carve(30408704);      // [4096][3712] (read by flash_attn; NOT aliased)
  bf16* Ob = (bf16*)carve(16777216);        // [4096][2048] dedicated
  bf16* LNout = (bf16*)carve(4194304);      // [4096][512]
  bf16* KPEb = (bf16*)carve(524288);        // [4096][64] bf16 (pre-rounded k_pe)
  bf16* zero16 = (bf16*)carve(256);         // zeroed 16B stub for K pad chunks
  char* KVT1 = carve(33554432);             // KVb [4096][4096]; reused as T1b [4096][2048]
  bf16* KVb = (bf16*)KVT1;
  bf16* T1b = (bf16*)KVT1;
  bf16* Vt = (bf16*)carve(18874368);        // [32][32][128][72]

  if (used > ws_size) return;  // workspace too small: fail cleanly, no OOB writes

  hipMemsetAsync(zero16, 0, 256, stream);   // pad source for K gather-staging

  cast_bf16<<<8192, 256, 0, stream>>>(hidden, Xb, 2097152);
  transpose_cast<<<dim3(96, 64), dim3(32, 8), 0, stream>>>(W_q, Wqkva_t, 2048, 3072, 3072);
  transpose_cast<<<dim3(20, 64), dim3(32, 8), 0, stream>>>(W_kva, Wqkva_t + (size_t)3072 * 2048,
                                                           2048, 576, 640);
  transpose_cast<<<dim3(128, 16), dim3(32, 8), 0, stream>>>(W_kvb, Wkvb_t, 512, 4096, 4096);
  transpose_cast<<<dim3(64, 64), dim3(32, 8), 0, stream>>>(W_o, Wo_t, 2048, 2048, 2048);

  // fused Q + KVA projection: [4096 x 3712] = Xb @ [Wq | Wkva]  (gemm2, GBM=16, GBN=29)
  gemm2_bt<bf16><<<16 * 29, 512, 0, stream>>>(Xb, Wqkva_t, QKVb, 4096, 3712, 2048, 16, 29);
  ln_rope<<<4096, 256, 0, stream>>>(QKVb, g, bta, pos, cosT, sinT, LNout, KPEb);
  gemm2_bt<bf16><<<16 * 32, 512, 0, stream>>>(LNout, Wkvb_t, KVb, 4096, 4096, 512, 16, 32);
  transpose_v<<<dim3(32, 64, 4), dim3(32, 8), 0, stream>>>(KVb, Vt);
  flash_attn<<<dim3(32, 32), 256, 0, stream>>>(QKVb, pos, cosT, sinT, KVb, KPEb, zero16, Vt, Ob);
  // W_o applied twice: 128² m97 structure + XCD-pinned grouping (GBN=16)
  gemm1g_bt<bf16><<<32 * 16, 256, 0, stream>>>(Ob, Wo_t, T1b, 4096, 2048, 2048, 16);
  gemm1g_bt<float><<<32 * 16, 256, 0, stream>>>(T1b, Wo_t, out, 4096, 2048, 2048, 16);
}

// Round 23
// 332.143 us; speedup vs baseline: 1.1102x; 1.0433x over previous
//
#include <hip/hip_runtime.h>

// ---------- types ----------
typedef __bf16 bf16;
typedef __bf16 bf16x4 __attribute__((ext_vector_type(4)));
typedef __bf16 bf16x8 __attribute__((ext_vector_type(8)));
typedef float  f32x4  __attribute__((ext_vector_type(4)));

__device__ __forceinline__ f32x4 mfma16(bf16x8 a, bf16x8 b, f32x4 c) {
  return __builtin_amdgcn_mfma_f32_16x16x32_bf16(a, b, c, 0, 0, 0);
}
// global -> LDS async copy, 16B per lane. LDS ptr must be wave-uniform base
// (HW adds lane*16); GLOBAL ptr is per-lane (enables gather-staging).
__device__ __forceinline__ void load_lds16(const void* g, void* l) {
  __builtin_amdgcn_global_load_lds((__attribute__((address_space(1))) void*)(g),
                                   (__attribute__((address_space(3))) void*)(l),
                                   16, 0, 0);
}

// ---------- elementwise casts ----------
__global__ void cast_bf16(const float* __restrict__ s, bf16* __restrict__ d, int n4) {
  int i = blockIdx.x * blockDim.x + threadIdx.x;
  if (i < n4) {
    float4 v = ((const float4*)s)[i];
    bf16x4 o = { (bf16)v.x, (bf16)v.y, (bf16)v.z, (bf16)v.w };
    *(bf16x4*)(d + (size_t)i * 4) = o;
  }
}

// src[K][N] f32 -> dst[Npad][K] bf16 (rows >= N zeroed)
__global__ void transpose_cast(const float* __restrict__ src, bf16* __restrict__ dst,
                               int K, int N, int Npad) {
  __shared__ float tile[32][33];
  const int n0 = blockIdx.x * 32, k0 = blockIdx.y * 32;
  const int tx = threadIdx.x, ty = threadIdx.y;
#pragma unroll
  for (int i = 0; i < 4; ++i) {
    int k = k0 + ty + i * 8, n = n0 + tx;
    tile[ty + i * 8][tx] = (k < K && n < N) ? src[(size_t)k * N + n] : 0.f;
  }
  __syncthreads();
#pragma unroll
  for (int i = 0; i < 4; ++i) {
    int n = n0 + ty + i * 8, k = k0 + tx;
    if (n < Npad && k < K) dst[(size_t)n * K + k] = (bf16)tile[tx][ty + i * 8];
  }
}

// ---------- GEMM v2 (large-K GEMMs: QKV, KVB): BM=256, BN=128, BK=32 ----------
// 512 threads = 8 waves (4M x 2N), dbuf LDS (48KB -> 3 blocks/CU), stage(t+1)
// issued before compute(t), one barrier per K-step. GROUP_M=8 ordering.
template <typename OutT>
__global__ __launch_bounds__(512) void gemm2_bt(
    const bf16* __restrict__ A, const bf16* __restrict__ Bt, OutT* __restrict__ C,
    int M, int N, int K, int GBM, int GBN) {
  __shared__ alignas(16) bf16 As[2][256 * 32];  // 16KB each
  __shared__ alignas(16) bf16 Bs[2][128 * 32];  //  8KB each
  const int wg = blockIdx.x;
  const int gsz = 8 * GBN;
  const int g = wg / gsz, rem = wg % gsz;
  const int bm = g * 8 + (rem % 8);
  const int bn = rem / 8;

  const int tid = threadIdx.x, wid = tid >> 6, lane = tid & 63;
  const int wr = wid >> 1, wc = wid & 1;  // wave grid 4(M) x 2(N)
  const int lo = lane & 15, hi = lane >> 4;
  const int w64 = wid * 64;

  f32x4 acc[4][4];
#pragma unroll
  for (int m = 0; m < 4; ++m)
#pragma unroll
    for (int n = 0; n < 4; ++n) acc[m][n] = f32x4{0.f, 0.f, 0.f, 0.f};

  const bf16* Abase = A + (size_t)(bm * 256) * K;
  const bf16* Bbase = Bt + (size_t)(bn * 128) * K;

  auto stage = [&](int buf, int kt) {
    int c = w64 + lane;
    load_lds16(Abase + (size_t)(c >> 2) * K + kt + (c & 3) * 8,
               &As[buf][0] + (size_t)w64 * 8);
    int c2 = 512 + w64 + lane;
    load_lds16(Abase + (size_t)(c2 >> 2) * K + kt + (c2 & 3) * 8,
               &As[buf][0] + (size_t)(512 + w64) * 8);
    load_lds16(Bbase + (size_t)(c >> 2) * K + kt + (c & 3) * 8,
               &Bs[buf][0] + (size_t)w64 * 8);
  };

  const int nt = K >> 5;
  stage(0, 0);
  __syncthreads();
  int cur = 0;
  for (int t = 0; t < nt; ++t) {
    if (t + 1 < nt) stage(cur ^ 1, (t + 1) << 5);  // issue prefetch FIRST
    bf16x8 af[4], bfr[4];
#pragma unroll
    for (int m = 0; m < 4; ++m)
      af[m] = *(const bf16x8*)(&As[cur][0] + (size_t)(wr * 64 + m * 16 + lo) * 32 + hi * 8);
#pragma unroll
    for (int n = 0; n < 4; ++n)
      bfr[n] = *(const bf16x8*)(&Bs[cur][0] + (size_t)(wc * 64 + n * 16 + lo) * 32 + hi * 8);
#pragma unroll
    for (int m = 0; m < 4; ++m)
#pragma unroll
      for (int n = 0; n < 4; ++n) acc[m][n] = mfma16(af[m], bfr[n], acc[m][n]);
    __syncthreads();  // drains prefetch DMA; guards buffer reuse
    cur ^= 1;
  }
#pragma unroll
  for (int m = 0; m < 4; ++m)
#pragma unroll
    for (int n = 0; n < 4; ++n)
#pragma unroll
      for (int r = 0; r < 4; ++r) {
        int row = bm * 256 + wr * 64 + m * 16 + hi * 4 + r;
        int col = bn * 128 + wc * 64 + n * 16 + lo;
        C[(size_t)row * N + col] = (OutT)acc[m][n][r];
      }
}

// ---------- GEMM 128² (Wo GEMMs only) + GROUP_M=8 XCD pinning ----------
template <typename OutT>
__global__ __launch_bounds__(256) void gemm1g_bt(
    const bf16* __restrict__ A, const bf16* __restrict__ Bt, OutT* __restrict__ C,
    int M, int N, int K, int GBN) {
  __shared__ alignas(16) bf16 As[128 * 32];
  __shared__ alignas(16) bf16 Bs[128 * 32];
  const int wg = blockIdx.x;
  const int gsz = 8 * GBN;
  const int g = wg / gsz, rem = wg % gsz;
  const int bm = g * 8 + (rem & 7);  // XCD (wg%8) <-> fixed bm within group
  const int bn = rem >> 3;
  const int tid = threadIdx.x, wid = tid >> 6, lane = tid & 63;
  const int wr = wid >> 1, wc = wid & 1;
  const int lo = lane & 15, hi = lane >> 4;
  f32x4 acc[4][4];
#pragma unroll
  for (int m = 0; m < 4; ++m)
#pragma unroll
    for (int n = 0; n < 4; ++n) acc[m][n] = f32x4{0.f, 0.f, 0.f, 0.f};

  const bf16* Abase = A + (size_t)(bm * 128) * K;
  const bf16* Bbase = Bt + (size_t)(bn * 128) * K;

  for (int kt = 0; kt < K; kt += 32) {
    __syncthreads();
    for (int c0 = wid * 64; c0 < 512; c0 += 256) {
      int c = c0 + lane;
      int row = c >> 2, kc = c & 3;
      load_lds16(Abase + (size_t)row * K + kt + kc * 8, As + (size_t)c0 * 8);
      load_lds16(Bbase + (size_t)row * K + kt + kc * 8, Bs + (size_t)c0 * 8);
    }
    __syncthreads();
    bf16x8 af[4], bfr[4];
#pragma unroll
    for (int m = 0; m < 4; ++m)
      af[m] = *(const bf16x8*)(As + (size_t)(wr * 64 + m * 16 + lo) * 32 + hi * 8);
#pragma unroll
    for (int n = 0; n < 4; ++n)
      bfr[n] = *(const bf16x8*)(Bs + (size_t)(wc * 64 + n * 16 + lo) * 32 + hi * 8);
#pragma unroll
    for (int m = 0; m < 4; ++m)
#pragma unroll
      for (int n = 0; n < 4; ++n) acc[m][n] = mfma16(af[m], bfr[n], acc[m][n]);
  }
#pragma unroll
  for (int m = 0; m < 4; ++m)
#pragma unroll
    for (int n = 0; n < 4; ++n)
#pragma unroll
      for (int r = 0; r < 4; ++r) {
        int row = bm * 128 + wr * 64 + m * 16 + hi * 4 + r;
        int col = bn * 128 + wc * 64 + n * 16 + lo;
        C[(size_t)row * N + col] = (OutT)acc[m][n][r];
      }
}

// ---------- LayerNorm(512) + RoPE on k_pe; KPE written as bf16 ----------
__global__ __launch_bounds__(256) void ln_rope(
    const bf16* __restrict__ QKVb, const float* __restrict__ g, const float* __restrict__ bta,
    const int* __restrict__ pos, const float* __restrict__ cosT, const float* __restrict__ sinT,
    bf16* __restrict__ LNout, bf16* __restrict__ KPEb) {
  const int row = blockIdx.x, tid = threadIdx.x;
  const bf16* x = QKVb + (size_t)row * 3712 + 3072;
  float v0 = (float)x[tid], v1 = (float)x[tid + 256];
  float s = v0 + v1, s2 = v0 * v0 + v1 * v1;
#pragma unroll
  for (int off = 1; off < 64; off <<= 1) {
    s += __shfl_xor(s, off, 64);
    s2 += __shfl_xor(s2, off, 64);
  }
  __shared__ float red[8];
  const int wid = tid >> 6;
  if ((tid & 63) == 0) { red[wid] = s; red[4 + wid] = s2; }
  __syncthreads();
  s = red[0] + red[1] + red[2] + red[3];
  s2 = red[4] + red[5] + red[6] + red[7];
  const float mu = s * (1.f / 512.f);
  const float var = s2 * (1.f / 512.f) - mu * mu;
  const float rstd = rsqrtf(var + 1e-6f);
  LNout[(size_t)row * 512 + tid] = (bf16)((v0 - mu) * rstd * g[tid] + bta[tid]);
  LNout[(size_t)row * 512 + tid + 256] = (bf16)((v1 - mu) * rstd * g[tid + 256] + bta[tid + 256]);
  if (tid < 64) {
    float kvp = (float)x[512 + tid];
    float partner = (float)x[512 + (tid ^ 32)];
    float rot = (tid < 32) ? -partner : partner;
    int p = pos[row];
    KPEb[(size_t)row * 64 + tid] = (bf16)(kvp * cosT[p * 64 + tid] + rot * sinT[p * 64 + tid]);
  }
}

// ---------- V transpose: [b][h][kv_tile][128 d][72 kv] (pad zeroed) ----------
__global__ void transpose_v(const bf16* __restrict__ KVb, bf16* __restrict__ Vt) {
  __shared__ bf16 tile[32][33];
  const int bh = blockIdx.x, st = blockIdx.y, dt = blockIdx.z;
  const int b = bh >> 4, h = bh & 15;
  const int tx = threadIdx.x, ty = threadIdx.y;
#pragma unroll
  for (int i = 0; i < 4; ++i) {
    int sIdx = st * 32 + ty + i * 8;
    tile[ty + i * 8][tx] = KVb[(size_t)(b * 2048 + sIdx) * 4096 + h * 256 + 128 + dt * 32 + tx];
  }
  __syncthreads();
  const int kt = st >> 1;
  const int kvl = (st & 1) * 32;
#pragma unroll
  for (int i = 0; i < 4; ++i) {
    int d = dt * 32 + ty + i * 8;
    size_t rowbase = ((size_t)(bh * 32 + kt) * 128 + d) * 72;
    Vt[rowbase + kvl + tx] = tile[tx][ty + i * 8];
    if ((st & 1) && tx < 8) Vt[rowbase + 64 + tx] = (bf16)0.f;
  }
}

// ---------- flash attention (causal) v6 + fused Q-RoPE + hoisted gather-K ----
// K staged directly from KVb/KPEb/zero16 via per-lane global addresses
// (pack_k + Kh eliminated). r23 fix: the chunk decomposition (div/mod +
// pointer selects) is HOISTED out of the kv0 loop — per-tile staging is just
// load + constant pointer increment (nope: 64*4096, pe: 64*64, pad: 0).
__global__ __launch_bounds__(256, 3) void flash_attn(
    const bf16* __restrict__ QKVb, const int* __restrict__ pos,
    const float* __restrict__ cosT, const float* __restrict__ sinT,
    const bf16* __restrict__ KVb, const bf16* __restrict__ KPEb,
    const bf16* __restrict__ zero16, const bf16* __restrict__ Vt,
    bf16* __restrict__ Ob) {
  __shared__ alignas(16) bf16 Ks[64 * 200];   // 25600 B
  __shared__ alignas(16) bf16 Vs[128 * 72];   // 18432 B
  __shared__ alignas(16) bf16 Ps[4][16 * 72]; //  9216 B
  const int bh = blockIdx.x, qt = 31 - blockIdx.y;  // longest blocks first
  const int b = bh >> 4, h = bh & 15;
  const int tid = threadIdx.x, wid = tid >> 6, lane = tid & 63;
  const int lo = lane & 15, hi = lane >> 4;
  const int q0 = qt * 64 + wid * 16;

  bf16x8 qf[6];
  {
    const int grow_i = b * 2048 + q0 + lo;
    const bf16* qsrc = QKVb + (size_t)grow_i * 3712 + h * 192 + hi * 8;
    bf16x8 raw[6];
#pragma unroll
    for (int kg = 0; kg < 6; ++kg) raw[kg] = *(const bf16x8*)(qsrc + kg * 32);
    const float scale = 0.07216878364870322f;  // 1/sqrt(192)
#pragma unroll
    for (int kg = 0; kg < 4; ++kg)
#pragma unroll
      for (int j = 0; j < 8; ++j) qf[kg][j] = (bf16)((float)raw[kg][j] * scale);
    const int p = pos[grow_i];
    const float* cb = cosT + p * 64 + hi * 8;
    const float* sb = sinT + p * 64 + hi * 8;
#pragma unroll
    for (int j = 0; j < 8; ++j) {
      float q4 = (float)raw[4][j], q5 = (float)raw[5][j];
      qf[4][j] = (bf16)((q4 * cb[j] - q5 * sb[j]) * scale);            // d<32: rot=-partner
      qf[5][j] = (bf16)((q5 * cb[32 + j] + q4 * sb[32 + j]) * scale);  // d>=32: rot=+partner
    }
  }
  float m_r[4] = {-INFINITY, -INFINITY, -INFINITY, -INFINITY};
  f32x4 accl = f32x4{0.f, 0.f, 0.f, 0.f};  // row-sum accumulator (l), D-layout
  f32x4 acc[8];
#pragma unroll
  for (int v = 0; v < 8; ++v) acc[v] = f32x4{0.f, 0.f, 0.f, 0.f};
  const bf16 one_b = (bf16)1.f;
  const bf16x8 ones = {one_b, one_b, one_b, one_b, one_b, one_b, one_b, one_b};

  // hoisted K gather decomposition: per-thread chunk slots are loop-invariant;
  // only kv0 advances -> constant per-slot pointer increments.
  const bf16* ksrc[7];
  int kstep[7];  // element step per 64-row tile
  {
    const bf16* KVbK = KVb + ((size_t)b * 2048) * 4096 + h * 256;
    const bf16* KPEbase = KPEb + ((size_t)b * 2048) * 64;
#pragma unroll
    for (int i = 0; i < 7; ++i) {
      int c0 = wid * 64 + i * 256;
      if (c0 < 1600) {
        unsigned c = c0 + lane;
        unsigned r = c / 25u;
        unsigned p = c - r * 25u;
        if (p < 16u) {
          ksrc[i] = KVbK + (size_t)r * 4096 + p * 8;
          kstep[i] = 64 * 4096;
        } else if (p < 24u) {
          ksrc[i] = KPEbase + (size_t)r * 64 + (p - 16u) * 8;
          kstep[i] = 64 * 64;
        } else {
          ksrc[i] = zero16;
          kstep[i] = 0;
        }
      } else {
        ksrc[i] = zero16;
        kstep[i] = 0;
      }
    }
  }
  const bf16* Vbase = Vt + (size_t)bh * 32 * (128 * 72);
  bf16* Pw = &Ps[wid][0];

  const int last = qt * 64;
  for (int kv0 = 0; kv0 <= last; kv0 += 64) {
    // stage K(t): pure load + pointer bump (decomposition hoisted)
#pragma unroll
    for (int i = 0; i < 7; ++i) {
      int c0 = wid * 64 + i * 256;
      if (c0 < 1600) {
        load_lds16(ksrc[i], Ks + (size_t)c0 * 8);
        ksrc[i] += kstep[i];
      }
    }
    // stage V(t) (linear copy, pre-transposed/padded)
    {
      const bf16* srcV = Vbase + (size_t)(kv0 >> 6) * (128 * 72);
      for (int c0 = wid * 64; c0 < 1152; c0 += 256)
        load_lds16(srcV + (size_t)(c0 + lane) * 8, Vs + (size_t)c0 * 8);
    }
    __syncthreads();  // #1: drain DMA (vmcnt0)

    // S = Q K^T  (per wave: 16 q x 64 kv)
    f32x4 sacc[4];
    __builtin_amdgcn_s_setprio(1);
#pragma unroll
    for (int nk = 0; nk < 4; ++nk) {
      sacc[nk] = f32x4{0.f, 0.f, 0.f, 0.f};
#pragma unroll
      for (int kg = 0; kg < 6; ++kg) {
        bf16x8 kf = *(const bf16x8*)(Ks + (size_t)(nk * 16 + lo) * 200 + kg * 32 + hi * 8);
        sacc[nk] = mfma16(qf[kg], kf, sacc[nk]);
      }
    }
    __builtin_amdgcn_s_setprio(0);
    if (kv0 == last) {  // diagonal tile: causal mask
#pragma unroll
      for (int nk = 0; nk < 4; ++nk)
#pragma unroll
        for (int r = 0; r < 4; ++r)
          if (kv0 + nk * 16 + lo > q0 + hi * 4 + r) sacc[nk][r] = -INFINITY;
    }
    // online softmax: max-reduce only (sum via ones-MFMA)
    float sc[4];
#pragma unroll
    for (int r = 0; r < 4; ++r) {
      float mx = fmaxf(fmaxf(sacc[0][r], sacc[1][r]), fmaxf(sacc[2][r], sacc[3][r]));
      mx = fmaxf(mx, __shfl_xor(mx, 1, 64));
      mx = fmaxf(mx, __shfl_xor(mx, 2, 64));
      mx = fmaxf(mx, __shfl_xor(mx, 4, 64));
      mx = fmaxf(mx, __shfl_xor(mx, 8, 64));
      float mnew = fmaxf(m_r[r], mx);
      sc[r] = __expf(m_r[r] - mnew);
      m_r[r] = mnew;
    }
#pragma unroll
    for (int nk = 0; nk < 4; ++nk)
#pragma unroll
      for (int r = 0; r < 4; ++r) {
        float p = __expf(sacc[nk][r] - m_r[r]);
        Pw[(hi * 4 + r) * 72 + nk * 16 + lo] = (bf16)p;
      }
#pragma unroll
    for (int r = 0; r < 4; ++r) {
      accl[r] *= sc[r];
#pragma unroll
      for (int v = 0; v < 8; ++v) acc[v][r] *= sc[r];
    }
    // P fragments (own-wave region; same-wave RAW via lgkmcnt, no barrier)
    bf16x8 pf0 = *(const bf16x8*)(Pw + (size_t)lo * 72 + hi * 8);
    bf16x8 pf1 = *(const bf16x8*)(Pw + (size_t)lo * 72 + 32 + hi * 8);
    __builtin_amdgcn_s_setprio(1);
    accl = mfma16(pf0, ones, accl);
    accl = mfma16(pf1, ones, accl);
    // PV: P (16 x 64) @ V (64 x 128); Vs holds V^T [d][kv]
#pragma unroll
    for (int v = 0; v < 8; ++v) {
      const bf16* vrow = Vs + (size_t)(v * 16 + lo) * 72 + hi * 8;
      bf16x8 vf0 = *(const bf16x8*)(vrow);
      bf16x8 vf1 = *(const bf16x8*)(vrow + 32);
      acc[v] = mfma16(pf0, vf0, acc[v]);
      acc[v] = mfma16(pf1, vf1, acc[v]);
    }
    __builtin_amdgcn_s_setprio(0);
    __syncthreads();  // #2: all K/V/P reads done before next tile's stage
  }
  // epilogue: O /= l, write bf16 to Ob[b][q][h*128+d]
#pragma unroll
  for (int r = 0; r < 4; ++r) {
    float invl = 1.f / accl[r];
    int qrow = q0 + hi * 4 + r;
    bf16* orow = Ob + ((size_t)b * 2048 + qrow) * 2048 + h * 128 + lo;
#pragma unroll
    for (int v = 0; v < 8; ++v) orow[v * 16] = (bf16)(acc[v][r] * invl);
  }
}

// ---------- launcher ----------
extern "C" void kernel_launch(void* const* d_in, const int* in_sizes, int n_in,
                              void* d_out, int out_size, void* d_ws, size_t ws_size,
                              hipStream_t stream) {
  const float* hidden = (const float*)d_in[0];
  const int* pos = (const int*)d_in[1];
  const float* cosT = (const float*)d_in[2];
  const float* sinT = (const float*)d_in[3];
  const float* W_q = (const float*)d_in[4];
  const float* W_kva = (const float*)d_in[5];
  const float* g = (const float*)d_in[6];
  const float* bta = (const float*)d_in[7];
  const float* W_kvb = (const float*)d_in[8];
  const float* W_o = (const float*)d_in[9];
  float* out = (float*)d_out;

  char* w = (char*)d_ws;
  size_t used = 0;
  auto carve = [&](size_t bytes) -> char* {
    char* p = w;
    size_t pad = (bytes + 255) & ~(size_t)255;
    w += pad;
    used += pad;
    return p;
  };
  bf16* Xb = (bf16*)carve(16777216);        // [4096][2048]
  bf16* Wqkva_t = (bf16*)carve(15204352);   // [3712][2048]: Wq rows 0..3071, Wkva rows 3072..3711
  bf16* Wkvb_t = (bf16*)carve(4194304);     // [4096][512]
  bf16* Wo_t = (bf16*)carve(8388608);       // [2048][2048]
  bf16* QKVb = (bf16*)carve(30408704);      // [4096][3712] (read by flash_attn; NOT aliased)
  bf16* Ob = (bf16*)carve(16777216);        // [4096][2048] dedicated
  bf16* LNout = (bf16*)carve(4194304);      // [4096][512]
  bf16* KPEb = (bf16*)carve(524288);        // [4096][64] bf16 (pre-rounded k_pe)
  bf16* zero16 = (bf16*)carve(256);         // zeroed 16B stub for K pad chunks
  char* KVT1 = carve(33554432);             // KVb [4096][4096]; reused as T1b [4096][2048]
  bf16* KVb = (bf16*)KVT1;
  bf16* T1b = (bf16*)KVT1;
  bf16* Vt = (bf16*)carve(18874368);        // [32][32][128][72]

  if (used > ws_size) return;  // workspace too small: fail cleanly, no OOB writes

  hipMemsetAsync(zero16, 0, 256, stream);   // pad source for K gather-staging

  cast_bf16<<<8192, 256, 0, stream>>>(hidden, Xb, 2097152);
  transpose_cast<<<dim3(96, 64), dim3(32, 8), 0, stream>>>(W_q, Wqkva_t, 2048, 3072, 3072);
  transpose_cast<<<dim3(20, 64), dim3(32, 8), 0, stream>>>(W_kva, Wqkva_t + (size_t)3072 * 2048,
                                                           2048, 576, 640);
  transpose_cast<<<dim3(128, 16), dim3(32, 8), 0, stream>>>(W_kvb, Wkvb_t, 512, 4096, 4096);
  transpose_cast<<<dim3(64, 64), dim3(32, 8), 0, stream>>>(W_o, Wo_t, 2048, 2048, 2048);

  // fused Q + KVA projection: [4096 x 3712] = Xb @ [Wq | Wkva]  (gemm2, GBM=16, GBN=29)
  gemm2_bt<bf16><<<16 * 29, 512, 0, stream>>>(Xb, Wqkva_t, QKVb, 4096, 3712, 2048, 16, 29);
  ln_rope<<<4096, 256, 0, stream>>>(QKVb, g, bta, pos, cosT, sinT, LNout, KPEb);
  gemm2_bt<bf16><<<16 * 32, 512, 0, stream>>>(LNout, Wkvb_t, KVb, 4096, 4096, 512, 16, 32);
  transpose_v<<<dim3(32, 64, 4), dim3(32, 8), 0, stream>>>(KVb, Vt);
  flash_attn<<<dim3(32, 32), 256, 0, stream>>>(QKVb, pos, cosT, sinT, KVb, KPEb, zero16, Vt, Ob);
  // W_o applied twice: 128² m97 structure + XCD-pinned grouping (GBN=16)
  gemm1g_bt<bf16><<<32 * 16, 256, 0, stream>>>(Ob, Wo_t, T1b, 4096, 2048, 2048, 16);
  gemm1g_bt<float><<<32 * 16, 256, 0, stream>>>(T1b, Wo_t, out, 4096, 2048, 2048, 16);
}

// Round 24
// 331.005 us; speedup vs baseline: 1.1140x; 1.0034x over previous
//
#include <hip/hip_runtime.h>

// ---------- types ----------
typedef __bf16 bf16;
typedef __bf16 bf16x4 __attribute__((ext_vector_type(4)));
typedef __bf16 bf16x8 __attribute__((ext_vector_type(8)));
typedef float  f32x4  __attribute__((ext_vector_type(4)));

__device__ __forceinline__ f32x4 mfma16(bf16x8 a, bf16x8 b, f32x4 c) {
  return __builtin_amdgcn_mfma_f32_16x16x32_bf16(a, b, c, 0, 0, 0);
}
// global -> LDS async copy, 16B per lane. LDS ptr must be wave-uniform base
// (HW adds lane*16); GLOBAL ptr is per-lane (enables gather-staging).
__device__ __forceinline__ void load_lds16(const void* g, void* l) {
  __builtin_amdgcn_global_load_lds((__attribute__((address_space(1))) void*)(g),
                                   (__attribute__((address_space(3))) void*)(l),
                                   16, 0, 0);
}

// ---------- elementwise casts ----------
__global__ void cast_bf16(const float* __restrict__ s, bf16* __restrict__ d, int n4) {
  int i = blockIdx.x * blockDim.x + threadIdx.x;
  if (i < n4) {
    float4 v = ((const float4*)s)[i];
    bf16x4 o = { (bf16)v.x, (bf16)v.y, (bf16)v.z, (bf16)v.w };
    *(bf16x4*)(d + (size_t)i * 4) = o;
  }
}

// src[K][N] f32 -> dst[Npad][K] bf16 (rows >= N zeroed)
__global__ void transpose_cast(const float* __restrict__ src, bf16* __restrict__ dst,
                               int K, int N, int Npad) {
  __shared__ float tile[32][33];
  const int n0 = blockIdx.x * 32, k0 = blockIdx.y * 32;
  const int tx = threadIdx.x, ty = threadIdx.y;
#pragma unroll
  for (int i = 0; i < 4; ++i) {
    int k = k0 + ty + i * 8, n = n0 + tx;
    tile[ty + i * 8][tx] = (k < K && n < N) ? src[(size_t)k * N + n] : 0.f;
  }
  __syncthreads();
#pragma unroll
  for (int i = 0; i < 4; ++i) {
    int n = n0 + ty + i * 8, k = k0 + tx;
    if (n < Npad && k < K) dst[(size_t)n * K + k] = (bf16)tile[tx][ty + i * 8];
  }
}

// ---------- GEMM v2 (large-K GEMMs: QKV, KVB): BM=256, BN=128, BK=32 ----------
// 512 threads = 8 waves (4M x 2N), dbuf LDS (48KB -> 3 blocks/CU), stage(t+1)
// issued before compute(t), one barrier per K-step. GROUP_M=8 ordering.
template <typename OutT>
__global__ __launch_bounds__(512) void gemm2_bt(
    const bf16* __restrict__ A, const bf16* __restrict__ Bt, OutT* __restrict__ C,
    int M, int N, int K, int GBM, int GBN) {
  __shared__ alignas(16) bf16 As[2][256 * 32];  // 16KB each
  __shared__ alignas(16) bf16 Bs[2][128 * 32];  //  8KB each
  const int wg = blockIdx.x;
  const int gsz = 8 * GBN;
  const int g = wg / gsz, rem = wg % gsz;
  const int bm = g * 8 + (rem % 8);
  const int bn = rem / 8;

  const int tid = threadIdx.x, wid = tid >> 6, lane = tid & 63;
  const int wr = wid >> 1, wc = wid & 1;  // wave grid 4(M) x 2(N)
  const int lo = lane & 15, hi = lane >> 4;
  const int w64 = wid * 64;

  f32x4 acc[4][4];
#pragma unroll
  for (int m = 0; m < 4; ++m)
#pragma unroll
    for (int n = 0; n < 4; ++n) acc[m][n] = f32x4{0.f, 0.f, 0.f, 0.f};

  const bf16* Abase = A + (size_t)(bm * 256) * K;
  const bf16* Bbase = Bt + (size_t)(bn * 128) * K;

  auto stage = [&](int buf, int kt) {
    int c = w64 + lane;
    load_lds16(Abase + (size_t)(c >> 2) * K + kt + (c & 3) * 8,
               &As[buf][0] + (size_t)w64 * 8);
    int c2 = 512 + w64 + lane;
    load_lds16(Abase + (size_t)(c2 >> 2) * K + kt + (c2 & 3) * 8,
               &As[buf][0] + (size_t)(512 + w64) * 8);
    load_lds16(Bbase + (size_t)(c >> 2) * K + kt + (c & 3) * 8,
               &Bs[buf][0] + (size_t)w64 * 8);
  };

  const int nt = K >> 5;
  stage(0, 0);
  __syncthreads();
  int cur = 0;
  for (int t = 0; t < nt; ++t) {
    if (t + 1 < nt) stage(cur ^ 1, (t + 1) << 5);  // issue prefetch FIRST
    bf16x8 af[4], bfr[4];
#pragma unroll
    for (int m = 0; m < 4; ++m)
      af[m] = *(const bf16x8*)(&As[cur][0] + (size_t)(wr * 64 + m * 16 + lo) * 32 + hi * 8);
#pragma unroll
    for (int n = 0; n < 4; ++n)
      bfr[n] = *(const bf16x8*)(&Bs[cur][0] + (size_t)(wc * 64 + n * 16 + lo) * 32 + hi * 8);
#pragma unroll
    for (int m = 0; m < 4; ++m)
#pragma unroll
      for (int n = 0; n < 4; ++n) acc[m][n] = mfma16(af[m], bfr[n], acc[m][n]);
    __syncthreads();  // drains prefetch DMA; guards buffer reuse
    cur ^= 1;
  }
#pragma unroll
  for (int m = 0; m < 4; ++m)
#pragma unroll
    for (int n = 0; n < 4; ++n)
#pragma unroll
      for (int r = 0; r < 4; ++r) {
        int row = bm * 256 + wr * 64 + m * 16 + hi * 4 + r;
        int col = bn * 128 + wc * 64 + n * 16 + lo;
        C[(size_t)row * N + col] = (OutT)acc[m][n][r];
      }
}

// ---------- GEMM 128² (Wo GEMMs only) + GROUP_M=8 XCD pinning ----------
template <typename OutT>
__global__ __launch_bounds__(256) void gemm1g_bt(
    const bf16* __restrict__ A, const bf16* __restrict__ Bt, OutT* __restrict__ C,
    int M, int N, int K, int GBN) {
  __shared__ alignas(16) bf16 As[128 * 32];
  __shared__ alignas(16) bf16 Bs[128 * 32];
  const int wg = blockIdx.x;
  const int gsz = 8 * GBN;
  const int g = wg / gsz, rem = wg % gsz;
  const int bm = g * 8 + (rem & 7);  // XCD (wg%8) <-> fixed bm within group
  const int bn = rem >> 3;
  const int tid = threadIdx.x, wid = tid >> 6, lane = tid & 63;
  const int wr = wid >> 1, wc = wid & 1;
  const int lo = lane & 15, hi = lane >> 4;
  f32x4 acc[4][4];
#pragma unroll
  for (int m = 0; m < 4; ++m)
#pragma unroll
    for (int n = 0; n < 4; ++n) acc[m][n] = f32x4{0.f, 0.f, 0.f, 0.f};

  const bf16* Abase = A + (size_t)(bm * 128) * K;
  const bf16* Bbase = Bt + (size_t)(bn * 128) * K;

  for (int kt = 0; kt < K; kt += 32) {
    __syncthreads();
    for (int c0 = wid * 64; c0 < 512; c0 += 256) {
      int c = c0 + lane;
      int row = c >> 2, kc = c & 3;
      load_lds16(Abase + (size_t)row * K + kt + kc * 8, As + (size_t)c0 * 8);
      load_lds16(Bbase + (size_t)row * K + kt + kc * 8, Bs + (size_t)c0 * 8);
    }
    __syncthreads();
    bf16x8 af[4], bfr[4];
#pragma unroll
    for (int m = 0; m < 4; ++m)
      af[m] = *(const bf16x8*)(As + (size_t)(wr * 64 + m * 16 + lo) * 32 + hi * 8);
#pragma unroll
    for (int n = 0; n < 4; ++n)
      bfr[n] = *(const bf16x8*)(Bs + (size_t)(wc * 64 + n * 16 + lo) * 32 + hi * 8);
#pragma unroll
    for (int m = 0; m < 4; ++m)
#pragma unroll
      for (int n = 0; n < 4; ++n) acc[m][n] = mfma16(af[m], bfr[n], acc[m][n]);
  }
#pragma unroll
  for (int m = 0; m < 4; ++m)
#pragma unroll
    for (int n = 0; n < 4; ++n)
#pragma unroll
      for (int r = 0; r < 4; ++r) {
        int row = bm * 128 + wr * 64 + m * 16 + hi * 4 + r;
        int col = bn * 128 + wc * 64 + n * 16 + lo;
        C[(size_t)row * N + col] = (OutT)acc[m][n][r];
      }
}

// ---------- LayerNorm(512) + RoPE on k_pe; KPE written as bf16 ----------
__global__ __launch_bounds__(256) void ln_rope(
    const bf16* __restrict__ QKVb, const float* __restrict__ g, const float* __restrict__ bta,
    const int* __restrict__ pos, const float* __restrict__ cosT, const float* __restrict__ sinT,
    bf16* __restrict__ LNout, bf16* __restrict__ KPEb) {
  const int row = blockIdx.x, tid = threadIdx.x;
  const bf16* x = QKVb + (size_t)row * 3712 + 3072;
  float v0 = (float)x[tid], v1 = (float)x[tid + 256];
  float s = v0 + v1, s2 = v0 * v0 + v1 * v1;
#pragma unroll
  for (int off = 1; off < 64; off <<= 1) {
    s += __shfl_xor(s, off, 64);
    s2 += __shfl_xor(s2, off, 64);
  }
  __shared__ float red[8];
  const int wid = tid >> 6;
  if ((tid & 63) == 0) { red[wid] = s; red[4 + wid] = s2; }
  __syncthreads();
  s = red[0] + red[1] + red[2] + red[3];
  s2 = red[4] + red[5] + red[6] + red[7];
  const float mu = s * (1.f / 512.f);
  const float var = s2 * (1.f / 512.f) - mu * mu;
  const float rstd = rsqrtf(var + 1e-6f);
  LNout[(size_t)row * 512 + tid] = (bf16)((v0 - mu) * rstd * g[tid] + bta[tid]);
  LNout[(size_t)row * 512 + tid + 256] = (bf16)((v1 - mu) * rstd * g[tid + 256] + bta[tid + 256]);
  if (tid < 64) {
    float kvp = (float)x[512 + tid];
    float partner = (float)x[512 + (tid ^ 32)];
    float rot = (tid < 32) ? -partner : partner;
    int p = pos[row];
    KPEb[(size_t)row * 64 + tid] = (bf16)(kvp * cosT[p * 64 + tid] + rot * sinT[p * 64 + tid]);
  }
}

// ---------- V transpose: [b][h][kv_tile][128 d][72 kv] (pad zeroed) ----------
__global__ void transpose_v(const bf16* __restrict__ KVb, bf16* __restrict__ Vt) {
  __shared__ bf16 tile[32][33];
  const int bh = blockIdx.x, st = blockIdx.y, dt = blockIdx.z;
  const int b = bh >> 4, h = bh & 15;
  const int tx = threadIdx.x, ty = threadIdx.y;
#pragma unroll
  for (int i = 0; i < 4; ++i) {
    int sIdx = st * 32 + ty + i * 8;
    tile[ty + i * 8][tx] = KVb[(size_t)(b * 2048 + sIdx) * 4096 + h * 256 + 128 + dt * 32 + tx];
  }
  __syncthreads();
  const int kt = st >> 1;
  const int kvl = (st & 1) * 32;
#pragma unroll
  for (int i = 0; i < 4; ++i) {
    int d = dt * 32 + ty + i * 8;
    size_t rowbase = ((size_t)(bh * 32 + kt) * 128 + d) * 72;
    Vt[rowbase + kvl + tx] = tile[tx][ty + i * 8];
    if ((st & 1) && tx < 8) Vt[rowbase + 64 + tx] = (bf16)0.f;
  }
}

// ---------- flash attention (causal) v6 + fused Q-RoPE + hoisted gather-K ----
// K staged directly from KVb/KPEb/zero16 via per-lane global addresses
// (pack_k + Kh eliminated); chunk decomposition hoisted out of the kv0 loop
// so per-tile staging is pure load + constant pointer increment.
__global__ __launch_bounds__(256, 3) void flash_attn(
    const bf16* __restrict__ QKVb, const int* __restrict__ pos,
    const float* __restrict__ cosT, const float* __restrict__ sinT,
    const bf16* __restrict__ KVb, const bf16* __restrict__ KPEb,
    const bf16* __restrict__ zero16, const bf16* __restrict__ Vt,
    bf16* __restrict__ Ob) {
  __shared__ alignas(16) bf16 Ks[64 * 200];   // 25600 B
  __shared__ alignas(16) bf16 Vs[128 * 72];   // 18432 B
  __shared__ alignas(16) bf16 Ps[4][16 * 72]; //  9216 B
  const int bh = blockIdx.x, qt = 31 - blockIdx.y;  // longest blocks first
  const int b = bh >> 4, h = bh & 15;
  const int tid = threadIdx.x, wid = tid >> 6, lane = tid & 63;
  const int lo = lane & 15, hi = lane >> 4;
  const int q0 = qt * 64 + wid * 16;

  bf16x8 qf[6];
  {
    const int grow_i = b * 2048 + q0 + lo;
    const bf16* qsrc = QKVb + (size_t)grow_i * 3712 + h * 192 + hi * 8;
    bf16x8 raw[6];
#pragma unroll
    for (int kg = 0; kg < 6; ++kg) raw[kg] = *(const bf16x8*)(qsrc + kg * 32);
    const float scale = 0.07216878364870322f;  // 1/sqrt(192)
#pragma unroll
    for (int kg = 0; kg < 4; ++kg)
#pragma unroll
      for (int j = 0; j < 8; ++j) qf[kg][j] = (bf16)((float)raw[kg][j] * scale);
    const int p = pos[grow_i];
    const float* cb = cosT + p * 64 + hi * 8;
    const float* sb = sinT + p * 64 + hi * 8;
#pragma unroll
    for (int j = 0; j < 8; ++j) {
      float q4 = (float)raw[4][j], q5 = (float)raw[5][j];
      qf[4][j] = (bf16)((q4 * cb[j] - q5 * sb[j]) * scale);            // d<32: rot=-partner
      qf[5][j] = (bf16)((q5 * cb[32 + j] + q4 * sb[32 + j]) * scale);  // d>=32: rot=+partner
    }
  }
  float m_r[4] = {-INFINITY, -INFINITY, -INFINITY, -INFINITY};
  f32x4 accl = f32x4{0.f, 0.f, 0.f, 0.f};  // row-sum accumulator (l), D-layout
  f32x4 acc[8];
#pragma unroll
  for (int v = 0; v < 8; ++v) acc[v] = f32x4{0.f, 0.f, 0.f, 0.f};
  const bf16 one_b = (bf16)1.f;
  const bf16x8 ones = {one_b, one_b, one_b, one_b, one_b, one_b, one_b, one_b};

  // hoisted K gather decomposition: per-thread chunk slots are loop-invariant;
  // only kv0 advances -> constant per-slot pointer increments.
  const bf16* ksrc[7];
  int kstep[7];  // element step per 64-row tile
  {
    const bf16* KVbK = KVb + ((size_t)b * 2048) * 4096 + h * 256;
    const bf16* KPEbase = KPEb + ((size_t)b * 2048) * 64;
#pragma unroll
    for (int i = 0; i < 7; ++i) {
      int c0 = wid * 64 + i * 256;
      if (c0 < 1600) {
        unsigned c = c0 + lane;
        unsigned r = c / 25u;
        unsigned p = c - r * 25u;
        if (p < 16u) {
          ksrc[i] = KVbK + (size_t)r * 4096 + p * 8;
          kstep[i] = 64 * 4096;
        } else if (p < 24u) {
          ksrc[i] = KPEbase + (size_t)r * 64 + (p - 16u) * 8;
          kstep[i] = 64 * 64;
        } else {
          ksrc[i] = zero16;
          kstep[i] = 0;
        }
      } else {
        ksrc[i] = zero16;
        kstep[i] = 0;
      }
    }
  }
  const bf16* Vbase = Vt + (size_t)bh * 32 * (128 * 72);
  bf16* Pw = &Ps[wid][0];

  const int last = qt * 64;
  for (int kv0 = 0; kv0 <= last; kv0 += 64) {
    // stage K(t): pure load + pointer bump (decomposition hoisted)
#pragma unroll
    for (int i = 0; i < 7; ++i) {
      int c0 = wid * 64 + i * 256;
      if (c0 < 1600) {
        load_lds16(ksrc[i], Ks + (size_t)c0 * 8);
        ksrc[i] += kstep[i];
      }
    }
    // stage V(t) (linear copy, pre-transposed/padded)
    {
      const bf16* srcV = Vbase + (size_t)(kv0 >> 6) * (128 * 72);
      for (int c0 = wid * 64; c0 < 1152; c0 += 256)
        load_lds16(srcV + (size_t)(c0 + lane) * 8, Vs + (size_t)c0 * 8);
    }
    __syncthreads();  // #1: drain DMA (vmcnt0)

    // S = Q K^T  (per wave: 16 q x 64 kv)
    f32x4 sacc[4];
    __builtin_amdgcn_s_setprio(1);
#pragma unroll
    for (int nk = 0; nk < 4; ++nk) {
      sacc[nk] = f32x4{0.f, 0.f, 0.f, 0.f};
#pragma unroll
      for (int kg = 0; kg < 6; ++kg) {
        bf16x8 kf = *(const bf16x8*)(Ks + (size_t)(nk * 16 + lo) * 200 + kg * 32 + hi * 8);
        sacc[nk] = mfma16(qf[kg], kf, sacc[nk]);
      }
    }
    __builtin_amdgcn_s_setprio(0);
    if (kv0 == last) {  // diagonal tile: causal mask
#pragma unroll
      for (int nk = 0; nk < 4; ++nk)
#pragma unroll
        for (int r = 0; r < 4; ++r)
          if (kv0 + nk * 16 + lo > q0 + hi * 4 + r) sacc[nk][r] = -INFINITY;
    }
    // online softmax: max-reduce only (sum via ones-MFMA)
    float sc[4];
#pragma unroll
    for (int r = 0; r < 4; ++r) {
      float mx = fmaxf(fmaxf(sacc[0][r], sacc[1][r]), fmaxf(sacc[2][r], sacc[3][r]));
      mx = fmaxf(mx, __shfl_xor(mx, 1, 64));
      mx = fmaxf(mx, __shfl_xor(mx, 2, 64));
      mx = fmaxf(mx, __shfl_xor(mx, 4, 64));
      mx = fmaxf(mx, __shfl_xor(mx, 8, 64));
      float mnew = fmaxf(m_r[r], mx);
      sc[r] = __expf(m_r[r] - mnew);
      m_r[r] = mnew;
    }
#pragma unroll
    for (int nk = 0; nk < 4; ++nk)
#pragma unroll
      for (int r = 0; r < 4; ++r) {
        float p = __expf(sacc[nk][r] - m_r[r]);
        Pw[(hi * 4 + r) * 72 + nk * 16 + lo] = (bf16)p;
      }
#pragma unroll
    for (int r = 0; r < 4; ++r) {
      accl[r] *= sc[r];
#pragma unroll
      for (int v = 0; v < 8; ++v) acc[v][r] *= sc[r];
    }
    // P fragments (own-wave region; same-wave RAW via lgkmcnt, no barrier)
    bf16x8 pf0 = *(const bf16x8*)(Pw + (size_t)lo * 72 + hi * 8);
    bf16x8 pf1 = *(const bf16x8*)(Pw + (size_t)lo * 72 + 32 + hi * 8);
    __builtin_amdgcn_s_setprio(1);
    accl = mfma16(pf0, ones, accl);
    accl = mfma16(pf1, ones, accl);
    // PV: P (16 x 64) @ V (64 x 128); Vs holds V^T [d][kv]
#pragma unroll
    for (int v = 0; v < 8; ++v) {
      const bf16* vrow = Vs + (size_t)(v * 16 + lo) * 72 + hi * 8;
      bf16x8 vf0 = *(const bf16x8*)(vrow);
      bf16x8 vf1 = *(const bf16x8*)(vrow + 32);
      acc[v] = mfma16(pf0, vf0, acc[v]);
      acc[v] = mfma16(pf1, vf1, acc[v]);
    }
    __builtin_amdgcn_s_setprio(0);
    __syncthreads();  // #2: all K/V/P reads done before next tile's stage
  }
  // epilogue: O /= l, write bf16 to Ob[b][q][h*128+d]
#pragma unroll
  for (int r = 0; r < 4; ++r) {
    float invl = 1.f / accl[r];
    int qrow = q0 + hi * 4 + r;
    bf16* orow = Ob + ((size_t)b * 2048 + qrow) * 2048 + h * 128 + lo;
#pragma unroll
    for (int v = 0; v < 8; ++v) orow[v * 16] = (bf16)(acc[v][r] * invl);
  }
}

// ---------- launcher ----------
extern "C" void kernel_launch(void* const* d_in, const int* in_sizes, int n_in,
                              void* d_out, int out_size, void* d_ws, size_t ws_size,
                              hipStream_t stream) {
  const float* hidden = (const float*)d_in[0];
  const int* pos = (const int*)d_in[1];
  const float* cosT = (const float*)d_in[2];
  const float* sinT = (const float*)d_in[3];
  const float* W_q = (const float*)d_in[4];
  const float* W_kva = (const float*)d_in[5];
  const float* g = (const float*)d_in[6];
  const float* bta = (const float*)d_in[7];
  const float* W_kvb = (const float*)d_in[8];
  const float* W_o = (const float*)d_in[9];
  float* out = (float*)d_out;

  char* w = (char*)d_ws;
  size_t used = 0;
  auto carve = [&](size_t bytes) -> char* {
    char* p = w;
    size_t pad = (bytes + 255) & ~(size_t)255;
    w += pad;
    used += pad;
    return p;
  };
  bf16* Xb = (bf16*)carve(16777216);        // [4096][2048]
  bf16* Wqkva_t = (bf16*)carve(15204352);   // [3712][2048]: Wq rows 0..3071, Wkva rows 3072..3711
  bf16* Wkvb_t = (bf16*)carve(4194304);     // [4096][512]
  bf16* Wo_t = (bf16*)carve(8388608);       // [2048][2048]
  bf16* QKVb = (bf16*)carve(30408704);      // [4096][3712] (read by flash_attn; NOT aliased)
  bf16* Ob = (bf16*)carve(16777216);        // [4096][2048] dedicated
  bf16* LNout = (bf16*)carve(4194304);      // [4096][512]
  bf16* KPEb = (bf16*)carve(524288);        // [4096][64] bf16 (pre-rounded k_pe)
  bf16* zero16 = (bf16*)carve(256);         // zeroed 16B stub for K pad chunks
  char* KVT1 = carve(33554432);             // KVb [4096][4096]; reused as T1b [4096][2048]
  bf16* KVb = (bf16*)KVT1;
  bf16* T1b = (bf16*)KVT1;
  bf16* Vt = (bf16*)carve(18874368);        // [32][32][128][72]

  if (used > ws_size) return;  // workspace too small: fail cleanly, no OOB writes

  hipMemsetAsync(zero16, 0, 256, stream);   // pad source for K gather-staging

  cast_bf16<<<8192, 256, 0, stream>>>(hidden, Xb, 2097152);
  transpose_cast<<<dim3(96, 64), dim3(32, 8), 0, stream>>>(W_q, Wqkva_t, 2048, 3072, 3072);
  transpose_cast<<<dim3(20, 64), dim3(32, 8), 0, stream>>>(W_kva, Wqkva_t + (size_t)3072 * 2048,
                                                           2048, 576, 640);
  transpose_cast<<<dim3(128, 16), dim3(32, 8), 0, stream>>>(W_kvb, Wkvb_t, 512, 4096, 4096);
  transpose_cast<<<dim3(64, 64), dim3(32, 8), 0, stream>>>(W_o, Wo_t, 2048, 2048, 2048);

  // fused Q + KVA projection: [4096 x 3712] = Xb @ [Wq | Wkva]  (gemm2, GBM=16, GBN=29)
  gemm2_bt<bf16><<<16 * 29, 512, 0, stream>>>(Xb, Wqkva_t, QKVb, 4096, 3712, 2048, 16, 29);
  ln_rope<<<4096, 256, 0, stream>>>(QKVb, g, bta, pos, cosT, sinT, LNout, KPEb);
  gemm2_bt<bf16><<<16 * 32, 512, 0, stream>>>(LNout, Wkvb_t, KVb, 4096, 4096, 512, 16, 32);
  transpose_v<<<dim3(32, 64, 4), dim3(32, 8), 0, stream>>>(KVb, Vt);
  flash_attn<<<dim3(32, 32), 256, 0, stream>>>(QKVb, pos, cosT, sinT, KVb, KPEb, zero16, Vt, Ob);
  // W_o applied twice: 128² m97 structure + XCD-pinned grouping (GBN=16)
  gemm1g_bt<bf16><<<32 * 16, 256, 0, stream>>>(Ob, Wo_t, T1b, 4096, 2048, 2048, 16);
  gemm1g_bt<float><<<32 * 16, 256, 0, stream>>>(T1b, Wo_t, out, 4096, 2048, 2048, 16);
}

// Round 25
// 329.821 us; speedup vs baseline: 1.1180x; 1.0036x over previous
//
#include <hip/hip_runtime.h>

// ---------- types ----------
typedef __bf16 bf16;
typedef __bf16 bf16x4 __attribute__((ext_vector_type(4)));
typedef __bf16 bf16x8 __attribute__((ext_vector_type(8)));
typedef float  f32x4  __attribute__((ext_vector_type(4)));

__device__ __forceinline__ f32x4 mfma16(bf16x8 a, bf16x8 b, f32x4 c) {
  return __builtin_amdgcn_mfma_f32_16x16x32_bf16(a, b, c, 0, 0, 0);
}
// global -> LDS async copy, 16B per lane. LDS ptr must be wave-uniform base
// (HW adds lane*16); GLOBAL ptr is per-lane (enables gather-staging).
__device__ __forceinline__ void load_lds16(const void* g, void* l) {
  __builtin_amdgcn_global_load_lds((__attribute__((address_space(1))) void*)(g),
                                   (__attribute__((address_space(3))) void*)(l),
                                   16, 0, 0);
}

// ---------- elementwise casts ----------
__global__ void cast_bf16(const float* __restrict__ s, bf16* __restrict__ d, int n4) {
  int i = blockIdx.x * blockDim.x + threadIdx.x;
  if (i < n4) {
    float4 v = ((const float4*)s)[i];
    bf16x4 o = { (bf16)v.x, (bf16)v.y, (bf16)v.z, (bf16)v.w };
    *(bf16x4*)(d + (size_t)i * 4) = o;
  }
}

// src[K][N] f32 -> dst[Npad][K] bf16 (rows >= N zeroed)
__global__ void transpose_cast(const float* __restrict__ src, bf16* __restrict__ dst,
                               int K, int N, int Npad) {
  __shared__ float tile[32][33];
  const int n0 = blockIdx.x * 32, k0 = blockIdx.y * 32;
  const int tx = threadIdx.x, ty = threadIdx.y;
#pragma unroll
  for (int i = 0; i < 4; ++i) {
    int k = k0 + ty + i * 8, n = n0 + tx;
    tile[ty + i * 8][tx] = (k < K && n < N) ? src[(size_t)k * N + n] : 0.f;
  }
  __syncthreads();
#pragma unroll
  for (int i = 0; i < 4; ++i) {
    int n = n0 + ty + i * 8, k = k0 + tx;
    if (n < Npad && k < K) dst[(size_t)n * K + k] = (bf16)tile[tx][ty + i * 8];
  }
}

// ---------- GEMM v2 (large-K GEMMs: QKV, KVB): BM=256, BN=128, BK=32 ----------
// 512 threads = 8 waves (4M x 2N), dbuf LDS (48KB -> 3 blocks/CU), stage(t+1)
// issued before compute(t), one barrier per K-step. GROUP_M=8 ordering.
template <typename OutT>
__global__ __launch_bounds__(512) void gemm2_bt(
    const bf16* __restrict__ A, const bf16* __restrict__ Bt, OutT* __restrict__ C,
    int M, int N, int K, int GBM, int GBN) {
  __shared__ alignas(16) bf16 As[2][256 * 32];  // 16KB each
  __shared__ alignas(16) bf16 Bs[2][128 * 32];  //  8KB each
  const int wg = blockIdx.x;
  const int gsz = 8 * GBN;
  const int g = wg / gsz, rem = wg % gsz;
  const int bm = g * 8 + (rem % 8);
  const int bn = rem / 8;

  const int tid = threadIdx.x, wid = tid >> 6, lane = tid & 63;
  const int wr = wid >> 1, wc = wid & 1;  // wave grid 4(M) x 2(N)
  const int lo = lane & 15, hi = lane >> 4;
  const int w64 = wid * 64;

  f32x4 acc[4][4];
#pragma unroll
  for (int m = 0; m < 4; ++m)
#pragma unroll
    for (int n = 0; n < 4; ++n) acc[m][n] = f32x4{0.f, 0.f, 0.f, 0.f};

  const bf16* Abase = A + (size_t)(bm * 256) * K;
  const bf16* Bbase = Bt + (size_t)(bn * 128) * K;

  auto stage = [&](int buf, int kt) {
    int c = w64 + lane;
    load_lds16(Abase + (size_t)(c >> 2) * K + kt + (c & 3) * 8,
               &As[buf][0] + (size_t)w64 * 8);
    int c2 = 512 + w64 + lane;
    load_lds16(Abase + (size_t)(c2 >> 2) * K + kt + (c2 & 3) * 8,
               &As[buf][0] + (size_t)(512 + w64) * 8);
    load_lds16(Bbase + (size_t)(c >> 2) * K + kt + (c & 3) * 8,
               &Bs[buf][0] + (size_t)w64 * 8);
  };

  const int nt = K >> 5;
  stage(0, 0);
  __syncthreads();
  int cur = 0;
  for (int t = 0; t < nt; ++t) {
    if (t + 1 < nt) stage(cur ^ 1, (t + 1) << 5);  // issue prefetch FIRST
    bf16x8 af[4], bfr[4];
#pragma unroll
    for (int m = 0; m < 4; ++m)
      af[m] = *(const bf16x8*)(&As[cur][0] + (size_t)(wr * 64 + m * 16 + lo) * 32 + hi * 8);
#pragma unroll
    for (int n = 0; n < 4; ++n)
      bfr[n] = *(const bf16x8*)(&Bs[cur][0] + (size_t)(wc * 64 + n * 16 + lo) * 32 + hi * 8);
#pragma unroll
    for (int m = 0; m < 4; ++m)
#pragma unroll
      for (int n = 0; n < 4; ++n) acc[m][n] = mfma16(af[m], bfr[n], acc[m][n]);
    __syncthreads();  // drains prefetch DMA; guards buffer reuse
    cur ^= 1;
  }
#pragma unroll
  for (int m = 0; m < 4; ++m)
#pragma unroll
    for (int n = 0; n < 4; ++n)
#pragma unroll
      for (int r = 0; r < 4; ++r) {
        int row = bm * 256 + wr * 64 + m * 16 + hi * 4 + r;
        int col = bn * 128 + wc * 64 + n * 16 + lo;
        C[(size_t)row * N + col] = (OutT)acc[m][n][r];
      }
}

// ---------- GEMM 128² (Wo GEMMs only) + GROUP_M=8 XCD pinning ----------
template <typename OutT>
__global__ __launch_bounds__(256) void gemm1g_bt(
    const bf16* __restrict__ A, const bf16* __restrict__ Bt, OutT* __restrict__ C,
    int M, int N, int K, int GBN) {
  __shared__ alignas(16) bf16 As[128 * 32];
  __shared__ alignas(16) bf16 Bs[128 * 32];
  const int wg = blockIdx.x;
  const int gsz = 8 * GBN;
  const int g = wg / gsz, rem = wg % gsz;
  const int bm = g * 8 + (rem & 7);  // XCD (wg%8) <-> fixed bm within group
  const int bn = rem >> 3;
  const int tid = threadIdx.x, wid = tid >> 6, lane = tid & 63;
  const int wr = wid >> 1, wc = wid & 1;
  const int lo = lane & 15, hi = lane >> 4;
  f32x4 acc[4][4];
#pragma unroll
  for (int m = 0; m < 4; ++m)
#pragma unroll
    for (int n = 0; n < 4; ++n) acc[m][n] = f32x4{0.f, 0.f, 0.f, 0.f};

  const bf16* Abase = A + (size_t)(bm * 128) * K;
  const bf16* Bbase = Bt + (size_t)(bn * 128) * K;

  for (int kt = 0; kt < K; kt += 32) {
    __syncthreads();
    for (int c0 = wid * 64; c0 < 512; c0 += 256) {
      int c = c0 + lane;
      int row = c >> 2, kc = c & 3;
      load_lds16(Abase + (size_t)row * K + kt + kc * 8, As + (size_t)c0 * 8);
      load_lds16(Bbase + (size_t)row * K + kt + kc * 8, Bs + (size_t)c0 * 8);
    }
    __syncthreads();
    bf16x8 af[4], bfr[4];
#pragma unroll
    for (int m = 0; m < 4; ++m)
      af[m] = *(const bf16x8*)(As + (size_t)(wr * 64 + m * 16 + lo) * 32 + hi * 8);
#pragma unroll
    for (int n = 0; n < 4; ++n)
      bfr[n] = *(const bf16x8*)(Bs + (size_t)(wc * 64 + n * 16 + lo) * 32 + hi * 8);
#pragma unroll
    for (int m = 0; m < 4; ++m)
#pragma unroll
      for (int n = 0; n < 4; ++n) acc[m][n] = mfma16(af[m], bfr[n], acc[m][n]);
  }
#pragma unroll
  for (int m = 0; m < 4; ++m)
#pragma unroll
    for (int n = 0; n < 4; ++n)
#pragma unroll
      for (int r = 0; r < 4; ++r) {
        int row = bm * 128 + wr * 64 + m * 16 + hi * 4 + r;
        int col = bn * 128 + wc * 64 + n * 16 + lo;
        C[(size_t)row * N + col] = (OutT)acc[m][n][r];
      }
}

// ---------- LayerNorm(512) + RoPE on k_pe; KPE written as bf16 ----------
__global__ __launch_bounds__(256) void ln_rope(
    const bf16* __restrict__ QKVb, const float* __restrict__ g, const float* __restrict__ bta,
    const int* __restrict__ pos, const float* __restrict__ cosT, const float* __restrict__ sinT,
    bf16* __restrict__ LNout, bf16* __restrict__ KPEb) {
  const int row = blockIdx.x, tid = threadIdx.x;
  const bf16* x = QKVb + (size_t)row * 3712 + 3072;
  float v0 = (float)x[tid], v1 = (float)x[tid + 256];
  float s = v0 + v1, s2 = v0 * v0 + v1 * v1;
#pragma unroll
  for (int off = 1; off < 64; off <<= 1) {
    s += __shfl_xor(s, off, 64);
    s2 += __shfl_xor(s2, off, 64);
  }
  __shared__ float red[8];
  const int wid = tid >> 6;
  if ((tid & 63) == 0) { red[wid] = s; red[4 + wid] = s2; }
  __syncthreads();
  s = red[0] + red[1] + red[2] + red[3];
  s2 = red[4] + red[5] + red[6] + red[7];
  const float mu = s * (1.f / 512.f);
  const float var = s2 * (1.f / 512.f) - mu * mu;
  const float rstd = rsqrtf(var + 1e-6f);
  LNout[(size_t)row * 512 + tid] = (bf16)((v0 - mu) * rstd * g[tid] + bta[tid]);
  LNout[(size_t)row * 512 + tid + 256] = (bf16)((v1 - mu) * rstd * g[tid + 256] + bta[tid + 256]);
  if (tid < 64) {
    float kvp = (float)x[512 + tid];
    float partner = (float)x[512 + (tid ^ 32)];
    float rot = (tid < 32) ? -partner : partner;
    int p = pos[row];
    KPEb[(size_t)row * 64 + tid] = (bf16)(kvp * cosT[p * 64 + tid] + rot * sinT[p * 64 + tid]);
  }
}

// ---------- V transpose: [b][h][kv_tile][128 d][72 kv] (pad zeroed) ----------
__global__ void transpose_v(const bf16* __restrict__ KVb, bf16* __restrict__ Vt) {
  __shared__ bf16 tile[32][33];
  const int bh = blockIdx.x, st = blockIdx.y, dt = blockIdx.z;
  const int b = bh >> 4, h = bh & 15;
  const int tx = threadIdx.x, ty = threadIdx.y;
#pragma unroll
  for (int i = 0; i < 4; ++i) {
    int sIdx = st * 32 + ty + i * 8;
    tile[ty + i * 8][tx] = KVb[(size_t)(b * 2048 + sIdx) * 4096 + h * 256 + 128 + dt * 32 + tx];
  }
  __syncthreads();
  const int kt = st >> 1;
  const int kvl = (st & 1) * 32;
#pragma unroll
  for (int i = 0; i < 4; ++i) {
    int d = dt * 32 + ty + i * 8;
    size_t rowbase = ((size_t)(bh * 32 + kt) * 128 + d) * 72;
    Vt[rowbase + kvl + tx] = tile[tx][ty + i * 8];
    if ((st & 1) && tx < 8) Vt[rowbase + 64 + tx] = (bf16)0.f;
  }
}

// ---------- flash attention (causal) v6 + fused Q-RoPE + hoisted gather-K ----
// K staged directly from KVb/KPEb/zero16 via per-lane global addresses
// (pack_k + Kh eliminated); chunk decomposition hoisted out of the kv0 loop
// so per-tile staging is pure load + constant pointer increment.
__global__ __launch_bounds__(256, 3) void flash_attn(
    const bf16* __restrict__ QKVb, const int* __restrict__ pos,
    const float* __restrict__ cosT, const float* __restrict__ sinT,
    const bf16* __restrict__ KVb, const bf16* __restrict__ KPEb,
    const bf16* __restrict__ zero16, const bf16* __restrict__ Vt,
    bf16* __restrict__ Ob) {
  __shared__ alignas(16) bf16 Ks[64 * 200];   // 25600 B
  __shared__ alignas(16) bf16 Vs[128 * 72];   // 18432 B
  __shared__ alignas(16) bf16 Ps[4][16 * 72]; //  9216 B
  const int bh = blockIdx.x, qt = 31 - blockIdx.y;  // longest blocks first
  const int b = bh >> 4, h = bh & 15;
  const int tid = threadIdx.x, wid = tid >> 6, lane = tid & 63;
  const int lo = lane & 15, hi = lane >> 4;
  const int q0 = qt * 64 + wid * 16;

  bf16x8 qf[6];
  {
    const int grow_i = b * 2048 + q0 + lo;
    const bf16* qsrc = QKVb + (size_t)grow_i * 3712 + h * 192 + hi * 8;
    bf16x8 raw[6];
#pragma unroll
    for (int kg = 0; kg < 6; ++kg) raw[kg] = *(const bf16x8*)(qsrc + kg * 32);
    const float scale = 0.07216878364870322f;  // 1/sqrt(192)
#pragma unroll
    for (int kg = 0; kg < 4; ++kg)
#pragma unroll
      for (int j = 0; j < 8; ++j) qf[kg][j] = (bf16)((float)raw[kg][j] * scale);
    const int p = pos[grow_i];
    const float* cb = cosT + p * 64 + hi * 8;
    const float* sb = sinT + p * 64 + hi * 8;
#pragma unroll
    for (int j = 0; j < 8; ++j) {
      float q4 = (float)raw[4][j], q5 = (float)raw[5][j];
      qf[4][j] = (bf16)((q4 * cb[j] - q5 * sb[j]) * scale);            // d<32: rot=-partner
      qf[5][j] = (bf16)((q5 * cb[32 + j] + q4 * sb[32 + j]) * scale);  // d>=32: rot=+partner
    }
  }
  float m_r[4] = {-INFINITY, -INFINITY, -INFINITY, -INFINITY};
  f32x4 accl = f32x4{0.f, 0.f, 0.f, 0.f};  // row-sum accumulator (l), D-layout
  f32x4 acc[8];
#pragma unroll
  for (int v = 0; v < 8; ++v) acc[v] = f32x4{0.f, 0.f, 0.f, 0.f};
  const bf16 one_b = (bf16)1.f;
  const bf16x8 ones = {one_b, one_b, one_b, one_b, one_b, one_b, one_b, one_b};

  // hoisted K gather decomposition: per-thread chunk slots are loop-invariant;
  // only kv0 advances -> constant per-slot pointer increments.
  const bf16* ksrc[7];
  int kstep[7];  // element step per 64-row tile
  {
    const bf16* KVbK = KVb + ((size_t)b * 2048) * 4096 + h * 256;
    const bf16* KPEbase = KPEb + ((size_t)b * 2048) * 64;
#pragma unroll
    for (int i = 0; i < 7; ++i) {
      int c0 = wid * 64 + i * 256;
      if (c0 < 1600) {
        unsigned c = c0 + lane;
        unsigned r = c / 25u;
        unsigned p = c - r * 25u;
        if (p < 16u) {
          ksrc[i] = KVbK + (size_t)r * 4096 + p * 8;
          kstep[i] = 64 * 4096;
        } else if (p < 24u) {
          ksrc[i] = KPEbase + (size_t)r * 64 + (p - 16u) * 8;
          kstep[i] = 64 * 64;
        } else {
          ksrc[i] = zero16;
          kstep[i] = 0;
        }
      } else {
        ksrc[i] = zero16;
        kstep[i] = 0;
      }
    }
  }
  const bf16* Vbase = Vt + (size_t)bh * 32 * (128 * 72);
  bf16* Pw = &Ps[wid][0];

  const int last = qt * 64;
  for (int kv0 = 0; kv0 <= last; kv0 += 64) {
    // stage K(t): pure load + pointer bump (decomposition hoisted)
#pragma unroll
    for (int i = 0; i < 7; ++i) {
      int c0 = wid * 64 + i * 256;
      if (c0 < 1600) {
        load_lds16(ksrc[i], Ks + (size_t)c0 * 8);
        ksrc[i] += kstep[i];
      }
    }
    // stage V(t) (linear copy, pre-transposed/padded)
    {
      const bf16* srcV = Vbase + (size_t)(kv0 >> 6) * (128 * 72);
      for (int c0 = wid * 64; c0 < 1152; c0 += 256)
        load_lds16(srcV + (size_t)(c0 + lane) * 8, Vs + (size_t)c0 * 8);
    }
    __syncthreads();  // #1: drain DMA (vmcnt0)

    // S = Q K^T  (per wave: 16 q x 64 kv)
    f32x4 sacc[4];
    __builtin_amdgcn_s_setprio(1);
#pragma unroll
    for (int nk = 0; nk < 4; ++nk) {
      sacc[nk] = f32x4{0.f, 0.f, 0.f, 0.f};
#pragma unroll
      for (int kg = 0; kg < 6; ++kg) {
        bf16x8 kf = *(const bf16x8*)(Ks + (size_t)(nk * 16 + lo) * 200 + kg * 32 + hi * 8);
        sacc[nk] = mfma16(qf[kg], kf, sacc[nk]);
      }
    }
    __builtin_amdgcn_s_setprio(0);
    if (kv0 == last) {  // diagonal tile: causal mask
#pragma unroll
      for (int nk = 0; nk < 4; ++nk)
#pragma unroll
        for (int r = 0; r < 4; ++r)
          if (kv0 + nk * 16 + lo > q0 + hi * 4 + r) sacc[nk][r] = -INFINITY;
    }
    // online softmax: max-reduce only (sum via ones-MFMA)
    float sc[4];
#pragma unroll
    for (int r = 0; r < 4; ++r) {
      float mx = fmaxf(fmaxf(sacc[0][r], sacc[1][r]), fmaxf(sacc[2][r], sacc[3][r]));
      mx = fmaxf(mx, __shfl_xor(mx, 1, 64));
      mx = fmaxf(mx, __shfl_xor(mx, 2, 64));
      mx = fmaxf(mx, __shfl_xor(mx, 4, 64));
      mx = fmaxf(mx, __shfl_xor(mx, 8, 64));
      float mnew = fmaxf(m_r[r], mx);
      sc[r] = __expf(m_r[r] - mnew);
      m_r[r] = mnew;
    }
#pragma unroll
    for (int nk = 0; nk < 4; ++nk)
#pragma unroll
      for (int r = 0; r < 4; ++r) {
        float p = __expf(sacc[nk][r] - m_r[r]);
        Pw[(hi * 4 + r) * 72 + nk * 16 + lo] = (bf16)p;
      }
#pragma unroll
    for (int r = 0; r < 4; ++r) {
      accl[r] *= sc[r];
#pragma unroll
      for (int v = 0; v < 8; ++v) acc[v][r] *= sc[r];
    }
    // P fragments (own-wave region; same-wave RAW via lgkmcnt, no barrier)
    bf16x8 pf0 = *(const bf16x8*)(Pw + (size_t)lo * 72 + hi * 8);
    bf16x8 pf1 = *(const bf16x8*)(Pw + (size_t)lo * 72 + 32 + hi * 8);
    __builtin_amdgcn_s_setprio(1);
    accl = mfma16(pf0, ones, accl);
    accl = mfma16(pf1, ones, accl);
    // PV: P (16 x 64) @ V (64 x 128); Vs holds V^T [d][kv]
#pragma unroll
    for (int v = 0; v < 8; ++v) {
      const bf16* vrow = Vs + (size_t)(v * 16 + lo) * 72 + hi * 8;
      bf16x8 vf0 = *(const bf16x8*)(vrow);
      bf16x8 vf1 = *(const bf16x8*)(vrow + 32);
      acc[v] = mfma16(pf0, vf0, acc[v]);
      acc[v] = mfma16(pf1, vf1, acc[v]);
    }
    __builtin_amdgcn_s_setprio(0);
    __syncthreads();  // #2: all K/V/P reads done before next tile's stage
  }
  // epilogue: O /= l, write bf16 to Ob[b][q][h*128+d]
#pragma unroll
  for (int r = 0; r < 4; ++r) {
    float invl = 1.f / accl[r];
    int qrow = q0 + hi * 4 + r;
    bf16* orow = Ob + ((size_t)b * 2048 + qrow) * 2048 + h * 128 + lo;
#pragma unroll
    for (int v = 0; v < 8; ++v) orow[v * 16] = (bf16)(acc[v][r] * invl);
  }
}

// ---------- launcher ----------
extern "C" void kernel_launch(void* const* d_in, const int* in_sizes, int n_in,
                              void* d_out, int out_size, void* d_ws, size_t ws_size,
                              hipStream_t stream) {
  const float* hidden = (const float*)d_in[0];
  const int* pos = (const int*)d_in[1];
  const float* cosT = (const float*)d_in[2];
  const float* sinT = (const float*)d_in[3];
  const float* W_q = (const float*)d_in[4];
  const float* W_kva = (const float*)d_in[5];
  const float* g = (const float*)d_in[6];
  const float* bta = (const float*)d_in[7];
  const float* W_kvb = (const float*)d_in[8];
  const float* W_o = (const float*)d_in[9];
  float* out = (float*)d_out;

  char* w = (char*)d_ws;
  size_t used = 0;
  auto carve = [&](size_t bytes) -> char* {
    char* p = w;
    size_t pad = (bytes + 255) & ~(size_t)255;
    w += pad;
    used += pad;
    return p;
  };
  bf16* Xb = (bf16*)carve(16777216);        // [4096][2048]
  bf16* Wqkva_t = (bf16*)carve(15204352);   // [3712][2048]: Wq rows 0..3071, Wkva rows 3072..3711
  bf16* Wkvb_t = (bf16*)carve(4194304);     // [4096][512]
  bf16* Wo_t = (bf16*)carve(8388608);       // [2048][2048]
  bf16* QKVb = (bf16*)carve(30408704);      // [4096][3712] (read by flash_attn; NOT aliased)
  bf16* Ob = (bf16*)carve(16777216);        // [4096][2048] dedicated
  bf16* LNout = (bf16*)carve(4194304);      // [4096][512]
  bf16* KPEb = (bf16*)carve(524288);        // [4096][64] bf16 (pre-rounded k_pe)
  bf16* zero16 = (bf16*)carve(256);         // zeroed 16B stub for K pad chunks
  char* KVT1 = carve(33554432);             // KVb [4096][4096]; reused as T1b [4096][2048]
  bf16* KVb = (bf16*)KVT1;
  bf16* T1b = (bf16*)KVT1;
  bf16* Vt = (bf16*)carve(18874368);        // [32][32][128][72]

  if (used > ws_size) return;  // workspace too small: fail cleanly, no OOB writes

  hipMemsetAsync(zero16, 0, 256, stream);   // pad source for K gather-staging

  cast_bf16<<<8192, 256, 0, stream>>>(hidden, Xb, 2097152);
  transpose_cast<<<dim3(96, 64), dim3(32, 8), 0, stream>>>(W_q, Wqkva_t, 2048, 3072, 3072);
  transpose_cast<<<dim3(20, 64), dim3(32, 8), 0, stream>>>(W_kva, Wqkva_t + (size_t)3072 * 2048,
                                                           2048, 576, 640);
  transpose_cast<<<dim3(128, 16), dim3(32, 8), 0, stream>>>(W_kvb, Wkvb_t, 512, 4096, 4096);
  transpose_cast<<<dim3(64, 64), dim3(32, 8), 0, stream>>>(W_o, Wo_t, 2048, 2048, 2048);

  // fused Q + KVA projection: [4096 x 3712] = Xb @ [Wq | Wkva]  (gemm2, GBM=16, GBN=29)
  gemm2_bt<bf16><<<16 * 29, 512, 0, stream>>>(Xb, Wqkva_t, QKVb, 4096, 3712, 2048, 16, 29);
  ln_rope<<<4096, 256, 0, stream>>>(QKVb, g, bta, pos, cosT, sinT, LNout, KPEb);
  gemm2_bt<bf16><<<16 * 32, 512, 0, stream>>>(LNout, Wkvb_t, KVb, 4096, 4096, 512, 16, 32);
  transpose_v<<<dim3(32, 64, 4), dim3(32, 8), 0, stream>>>(KVb, Vt);
  flash_attn<<<dim3(32, 32), 256, 0, stream>>>(QKVb, pos, cosT, sinT, KVb, KPEb, zero16, Vt, Ob);
  // W_o applied twice: 128² m97 structure + XCD-pinned grouping (GBN=16)
  gemm1g_bt<bf16><<<32 * 16, 256, 0, stream>>>(Ob, Wo_t, T1b, 4096, 2048, 2048, 16);
  gemm1g_bt<float><<<32 * 16, 256, 0, stream>>>(T1b, Wo_t, out, 4096, 2048, 2048, 16);
}